// Round 1
// baseline (220.915 us; speedup 1.0000x reference)
//
#include <hip/hip_runtime.h>
#include <hip/hip_bf16.h>

#define N_NODES 2048
#define IN_DIM 512
#define OUT_DIM 512
#define HEADS 8
#define HEAD_DIM 64
#define NEG_SLOPE 0.2f

// ---------------------------------------------------------------------------
// Kernel 1: Wh = x @ W   (2048x512 @ 512x512, f32)
// BM=BN=64, BK=16, 256 threads (16x16), 4x4 micro-tile per thread.
// ---------------------------------------------------------------------------
__global__ __launch_bounds__(256) void gemm_xw(
    const float* __restrict__ X, const float* __restrict__ W,
    float* __restrict__ Wh) {
  __shared__ float As[16][68];  // [k][m], padded: store-bank-conflict-free
  __shared__ float Bs[16][64];  // [k][n]

  const int t = threadIdx.x;
  const int tx = t & 15, ty = t >> 4;
  const int bm = blockIdx.x * 64;
  const int bn = blockIdx.y * 64;

  float c[4][4] = {};

  for (int k0 = 0; k0 < IN_DIM; k0 += 16) {
    // A tile 64x16 -> As[k][m] (transposed store). thread: row=t>>2, kq=(t&3)*4
    {
      const int row = t >> 2, kq = (t & 3) * 4;
      const float4 v =
          *(const float4*)&X[(bm + row) * IN_DIM + k0 + kq];
      As[kq + 0][row] = v.x;
      As[kq + 1][row] = v.y;
      As[kq + 2][row] = v.z;
      As[kq + 3][row] = v.w;
    }
    // B tile 16x64, natural layout, float4 per thread
    {
      const int flat = t * 4;
      const int kk = flat >> 6, nn = flat & 63;
      *(float4*)&Bs[kk][nn] = *(const float4*)&W[(k0 + kk) * OUT_DIM + bn + nn];
    }
    __syncthreads();
#pragma unroll
    for (int k = 0; k < 16; ++k) {
      const float4 av = *(const float4*)&As[k][ty * 4];
      const float4 bv = *(const float4*)&Bs[k][tx * 4];
      const float am[4] = {av.x, av.y, av.z, av.w};
      const float bb[4] = {bv.x, bv.y, bv.z, bv.w};
#pragma unroll
      for (int mm = 0; mm < 4; ++mm)
#pragma unroll
        for (int nn = 0; nn < 4; ++nn) c[mm][nn] += am[mm] * bb[nn];
    }
    __syncthreads();
  }

#pragma unroll
  for (int mm = 0; mm < 4; ++mm) {
    float4 v = make_float4(c[mm][0], c[mm][1], c[mm][2], c[mm][3]);
    *(float4*)&Wh[(bm + ty * 4 + mm) * OUT_DIM + bn + tx * 4] = v;
  }
}

// ---------------------------------------------------------------------------
// Kernel 2: s_src[h][n] = dot(Wh[n,h,:], a[:64]); s_dst[h][n] = dot(., a[64:])
// One wave per node; lane = d; shuffle reduce.
// ---------------------------------------------------------------------------
__global__ __launch_bounds__(256) void compute_s(
    const float* __restrict__ Wh, const float* __restrict__ a,
    float* __restrict__ s_src, float* __restrict__ s_dst) {
  const int lane = threadIdx.x & 63;
  const int w = threadIdx.x >> 6;
  const int n = blockIdx.x * 4 + w;
  const float asrc = a[lane];
  const float adst = a[64 + lane];
#pragma unroll
  for (int h = 0; h < HEADS; ++h) {
    const float v = Wh[n * OUT_DIM + h * HEAD_DIM + lane];
    float r1 = v * asrc, r2 = v * adst;
#pragma unroll
    for (int off = 32; off; off >>= 1) {
      r1 += __shfl_xor(r1, off);
      r2 += __shfl_xor(r2, off);
    }
    if (lane == 0) {
      s_src[h * N_NODES + n] = r1;
      s_dst[h * N_NODES + n] = r2;
    }
  }
}

// ---------------------------------------------------------------------------
// Kernel 3: fused masked softmax + alpha@Wh, flash style.
// grid = (N/16, HEADS). block = 256 threads = 4 waves; each wave owns 4 i-rows,
// lane = output dim d. j loop in 64-wide tiles: stage Wh tile in LDS, compute
// p = exp(leakyrelu(s_i + s_j)) * mask into LDS, then rank-64 accumulate.
// ---------------------------------------------------------------------------
__global__ __launch_bounds__(256) void attn(
    const float* __restrict__ Wh, const int* __restrict__ adj,
    const float* __restrict__ s_src, const float* __restrict__ s_dst,
    float* __restrict__ out) {
  __shared__ float whs[64][64];     // [jj][d]
  __shared__ float pls[4][4][64];   // [wave][i][jj]

  const int t = threadIdx.x;
  const int lane = t & 63;
  const int w = t >> 6;
  const int h = blockIdx.y;
  const int i0 = blockIdx.x * 16 + w * 4;

  float si[4];
#pragma unroll
  for (int i = 0; i < 4; ++i) si[i] = s_src[h * N_NODES + i0 + i];

  float acc[4] = {0.f, 0.f, 0.f, 0.f};
  float dpart[4] = {0.f, 0.f, 0.f, 0.f};

  for (int j0 = 0; j0 < N_NODES; j0 += 64) {
    __syncthreads();  // protect whs/pls reads from previous iteration
    // stage Wh tile: 64x64 floats; 256 threads x 4 float4
#pragma unroll
    for (int r = 0; r < 4; ++r) {
      const int flat = (t + r * 256) * 4;
      const int jj = flat >> 6, d = flat & 63;
      *(float4*)&whs[jj][d] =
          *(const float4*)&Wh[(j0 + jj) * OUT_DIM + h * HEAD_DIM + d];
    }
    // p phase: this lane handles jj = lane for its wave's 4 i-rows
    const float sj = s_dst[h * N_NODES + j0 + lane];
#pragma unroll
    for (int i = 0; i < 4; ++i) {
      const int m = adj[(size_t)(i0 + i) * N_NODES + j0 + lane];
      float e = si[i] + sj;
      e = (e >= 0.f) ? e : NEG_SLOPE * e;
      const float p = (m > 0) ? __expf(e) : 0.0f;
      pls[w][i][lane] = p;
      dpart[i] += p;
    }
    __syncthreads();
    // FMA phase: acc[i] += sum_jj p[i][jj] * whs[jj][lane]
#pragma unroll
    for (int jt = 0; jt < 64; jt += 4) {
      const float4 p0 = *(const float4*)&pls[w][0][jt];
      const float4 p1 = *(const float4*)&pls[w][1][jt];
      const float4 p2 = *(const float4*)&pls[w][2][jt];
      const float4 p3 = *(const float4*)&pls[w][3][jt];
      const float w0 = whs[jt + 0][lane];
      const float w1 = whs[jt + 1][lane];
      const float w2 = whs[jt + 2][lane];
      const float w3 = whs[jt + 3][lane];
      acc[0] += p0.x * w0 + p0.y * w1 + p0.z * w2 + p0.w * w3;
      acc[1] += p1.x * w0 + p1.y * w1 + p1.z * w2 + p1.w * w3;
      acc[2] += p2.x * w0 + p2.y * w1 + p2.z * w2 + p2.w * w3;
      acc[3] += p3.x * w0 + p3.y * w1 + p3.z * w2 + p3.w * w3;
    }
  }

  // reduce denominators across the wave (each lane summed its own jj slices)
#pragma unroll
  for (int i = 0; i < 4; ++i) {
#pragma unroll
    for (int off = 32; off; off >>= 1) dpart[i] += __shfl_xor(dpart[i], off);
  }
#pragma unroll
  for (int i = 0; i < 4; ++i) {
    out[(size_t)(i0 + i) * OUT_DIM + h * HEAD_DIM + lane] = acc[i] / dpart[i];
  }
}

// ---------------------------------------------------------------------------
extern "C" void kernel_launch(void* const* d_in, const int* in_sizes, int n_in,
                              void* d_out, int out_size, void* d_ws,
                              size_t ws_size, hipStream_t stream) {
  const float* x = (const float*)d_in[0];
  const int* adj = (const int*)d_in[1];
  const float* W = (const float*)d_in[2];
  const float* a = (const float*)d_in[3];
  float* out = (float*)d_out;

  float* Wh = (float*)d_ws;                       // 2048*512 f32 = 4 MB
  float* s_src = Wh + (size_t)N_NODES * OUT_DIM;  // 8*2048 f32
  float* s_dst = s_src + (size_t)HEADS * N_NODES;

  gemm_xw<<<dim3(N_NODES / 64, OUT_DIM / 64), 256, 0, stream>>>(x, W, Wh);
  compute_s<<<N_NODES / 4, 256, 0, stream>>>(Wh, a, s_src, s_dst);
  attn<<<dim3(N_NODES / 16, HEADS), 256, 0, stream>>>(Wh, adj, s_src, s_dst,
                                                      out);
}

// Round 2
// 106.032 us; speedup vs baseline: 2.0835x; 2.0835x over previous
//
#include <hip/hip_runtime.h>
#include <hip/hip_bf16.h>

#define N_NODES 2048
#define IN_DIM 512
#define OUT_DIM 512
#define HEADS 8
#define HEAD_DIM 64
#define NEG_SLOPE 0.2f

typedef float f32x4 __attribute__((ext_vector_type(4)));
typedef short bf16x8 __attribute__((ext_vector_type(8)));

// ---------------------------------------------------------------------------
// Kernel 1: Wh = x @ W   (2048x512 @ 512x512, f32)
// ---------------------------------------------------------------------------
__global__ __launch_bounds__(256) void gemm_xw(
    const float* __restrict__ X, const float* __restrict__ W,
    float* __restrict__ Wh) {
  __shared__ float As[16][68];
  __shared__ float Bs[16][64];

  const int t = threadIdx.x;
  const int tx = t & 15, ty = t >> 4;
  const int bm = blockIdx.x * 64;
  const int bn = blockIdx.y * 64;

  float c[4][4] = {};

  for (int k0 = 0; k0 < IN_DIM; k0 += 16) {
    {
      const int row = t >> 2, kq = (t & 3) * 4;
      const float4 v = *(const float4*)&X[(bm + row) * IN_DIM + k0 + kq];
      As[kq + 0][row] = v.x;
      As[kq + 1][row] = v.y;
      As[kq + 2][row] = v.z;
      As[kq + 3][row] = v.w;
    }
    {
      const int flat = t * 4;
      const int kk = flat >> 6, nn = flat & 63;
      *(float4*)&Bs[kk][nn] = *(const float4*)&W[(k0 + kk) * OUT_DIM + bn + nn];
    }
    __syncthreads();
#pragma unroll
    for (int k = 0; k < 16; ++k) {
      const float4 av = *(const float4*)&As[k][ty * 4];
      const float4 bv = *(const float4*)&Bs[k][tx * 4];
      const float am[4] = {av.x, av.y, av.z, av.w};
      const float bb[4] = {bv.x, bv.y, bv.z, bv.w};
#pragma unroll
      for (int mm = 0; mm < 4; ++mm)
#pragma unroll
        for (int nn = 0; nn < 4; ++nn) c[mm][nn] += am[mm] * bb[nn];
    }
    __syncthreads();
  }

#pragma unroll
  for (int mm = 0; mm < 4; ++mm) {
    float4 v = make_float4(c[mm][0], c[mm][1], c[mm][2], c[mm][3]);
    *(float4*)&Wh[(bm + ty * 4 + mm) * OUT_DIM + bn + tx * 4] = v;
  }
}

// ---------------------------------------------------------------------------
// Kernel 2: s_src[h][n], s_dst[h][n] from Wh rows
// ---------------------------------------------------------------------------
__global__ __launch_bounds__(256) void compute_s(
    const float* __restrict__ Wh, const float* __restrict__ a,
    float* __restrict__ s_src, float* __restrict__ s_dst) {
  const int lane = threadIdx.x & 63;
  const int w = threadIdx.x >> 6;
  const int n = blockIdx.x * 4 + w;
  const float asrc = a[lane];
  const float adst = a[64 + lane];
#pragma unroll
  for (int h = 0; h < HEADS; ++h) {
    const float v = Wh[n * OUT_DIM + h * HEAD_DIM + lane];
    float r1 = v * asrc, r2 = v * adst;
#pragma unroll
    for (int off = 32; off; off >>= 1) {
      r1 += __shfl_xor(r1, off);
      r2 += __shfl_xor(r2, off);
    }
    if (lane == 0) {
      s_src[h * N_NODES + n] = r1;
      s_dst[h * N_NODES + n] = r2;
    }
  }
}

// ---------------------------------------------------------------------------
// Kernel 3: WhT[od][n] = bf16(Wh[n][od])  (512 x 2048 bf16)
// ---------------------------------------------------------------------------
__global__ __launch_bounds__(256) void transpose_wh(
    const float* __restrict__ Wh, __hip_bfloat16* __restrict__ WhT) {
  __shared__ float tile[64][65];
  const int t = threadIdx.x;
  const int n0 = blockIdx.x * 64;
  const int od0 = blockIdx.y * 64;
#pragma unroll
  for (int rr = 0; rr < 16; ++rr) {
    const int nl = rr * 4 + (t >> 6);
    tile[nl][t & 63] = Wh[(size_t)(n0 + nl) * OUT_DIM + od0 + (t & 63)];
  }
  __syncthreads();
#pragma unroll
  for (int rr = 0; rr < 16; ++rr) {
    const int odl = rr * 4 + (t >> 6);
    WhT[(size_t)(od0 + odl) * N_NODES + n0 + (t & 63)] =
        __float2bfloat16(tile[t & 63][odl]);
  }
}

// ---------------------------------------------------------------------------
// Kernel 4: pack adj int32 -> bitmask. adjbits[row][grp] = 64 j-bits.
// ---------------------------------------------------------------------------
__global__ __launch_bounds__(256) void pack_adj(
    const int* __restrict__ adj, unsigned long long* __restrict__ adjbits) {
  const int t = threadIdx.x;
  const int lane = t & 63;
  const int w = t >> 6;
  const int g = blockIdx.x * 4 + w;  // 0 .. 2048*32-1
  const int rowi = g >> 5;
  const int grp = g & 31;
  const int m = adj[(size_t)rowi * N_NODES + grp * 64 + lane];
  const unsigned long long mask = __ballot(m > 0);
  if (lane == 0) adjbits[(size_t)rowi * 32 + grp] = mask;
}

// ---------------------------------------------------------------------------
// Kernel 5: fused masked softmax + P @ Wh via MFMA.
// grid = (N/16, HEADS), 256 threads = 4 waves; waves split the j range.
// Each lane computes its own A-fragment elems of P (row = lane&15,
// k = (lane>>4)*8+u) -> no LDS for P. B-frags are 16B loads from WhT.
// ---------------------------------------------------------------------------
__global__ __launch_bounds__(256) void attn_mfma(
    const __hip_bfloat16* __restrict__ WhT,
    const unsigned char* __restrict__ adjbits,
    const float* __restrict__ s_src, const float* __restrict__ s_dst,
    float* __restrict__ out) {
  __shared__ float acc_lds[4][16][68];
  __shared__ float den_lds[4][16];

  const int t = threadIdx.x;
  const int lane = t & 63;
  const int w = t >> 6;
  const int h = blockIdx.y;
  const int i0 = blockIdx.x * 16;
  const int row = lane & 15;   // A-row / B-col / C-col index
  const int kgrp = lane >> 4;  // 0..3 : k-slice group

  const float si = s_src[h * N_NODES + i0 + row];
  const unsigned char* __restrict__ abrow =
      adjbits + (size_t)(i0 + row) * (N_NODES / 8);

  f32x4 acc[4] = {};  // 4 n-tiles of 16 output dims
  float den = 0.f;

  for (int tt = 0; tt < 8; ++tt) {
    const int j0 = (w * 8 + tt) * 64;
    bf16x8 afrag[2];
#pragma unroll
    for (int ks = 0; ks < 2; ++ks) {
      const int jj = j0 + ks * 32 + kgrp * 8;
      const unsigned int mbyte = abrow[jj >> 3];
      const float4 sj0 = *(const float4*)&s_dst[h * N_NODES + jj];
      const float4 sj1 = *(const float4*)&s_dst[h * N_NODES + jj + 4];
      const float sjs[8] = {sj0.x, sj0.y, sj0.z, sj0.w,
                            sj1.x, sj1.y, sj1.z, sj1.w};
#pragma unroll
      for (int u = 0; u < 8; ++u) {
        float e = si + sjs[u];
        e = (e >= 0.f) ? e : NEG_SLOPE * e;
        const float p = ((mbyte >> u) & 1u) ? __expf(e) : 0.f;
        den += p;
        __hip_bfloat16 b = __float2bfloat16(p);
        afrag[ks][u] = *reinterpret_cast<const short*>(&b);
      }
    }
#pragma unroll
    for (int nt = 0; nt < 4; ++nt) {
      const size_t odbase = (size_t)(h * 64 + nt * 16 + row) * N_NODES;
#pragma unroll
      for (int ks = 0; ks < 2; ++ks) {
        const bf16x8 bfrag =
            *(const bf16x8*)&WhT[odbase + j0 + ks * 32 + kgrp * 8];
        acc[nt] = __builtin_amdgcn_mfma_f32_16x16x32_bf16(afrag[ks], bfrag,
                                                          acc[nt], 0, 0, 0);
      }
    }
  }

  // write per-wave partials: C layout col=lane&15, row=(lane>>4)*4+reg
#pragma unroll
  for (int nt = 0; nt < 4; ++nt)
#pragma unroll
    for (int r = 0; r < 4; ++r)
      acc_lds[w][kgrp * 4 + r][nt * 16 + row] = acc[nt][r];

  // denominator: lanes l, l^16, l^32, l^48 share the same row
  den += __shfl_xor(den, 16);
  den += __shfl_xor(den, 32);
  if (lane < 16) den_lds[w][lane] = den;
  __syncthreads();

  // final cross-wave reduce + normalize + store
  const int d = t & 63;
#pragma unroll
  for (int rr = 0; rr < 4; ++rr) {
    const int m = rr * 4 + (t >> 6);
    float v = acc_lds[0][m][d] + acc_lds[1][m][d] + acc_lds[2][m][d] +
              acc_lds[3][m][d];
    float dd = den_lds[0][m] + den_lds[1][m] + den_lds[2][m] + den_lds[3][m];
    out[(size_t)(i0 + m) * OUT_DIM + h * HEAD_DIM + d] = v / dd;
  }
}

// ---------------------------------------------------------------------------
extern "C" void kernel_launch(void* const* d_in, const int* in_sizes, int n_in,
                              void* d_out, int out_size, void* d_ws,
                              size_t ws_size, hipStream_t stream) {
  const float* x = (const float*)d_in[0];
  const int* adj = (const int*)d_in[1];
  const float* W = (const float*)d_in[2];
  const float* a = (const float*)d_in[3];
  float* out = (float*)d_out;

  char* ws = (char*)d_ws;
  float* Wh = (float*)ws;                                   // 4 MB
  __hip_bfloat16* WhT = (__hip_bfloat16*)(ws + (4 << 20));  // 2 MB
  float* s_src = (float*)(ws + (6 << 20));                  // 64 KB
  float* s_dst = (float*)(ws + (6 << 20) + (64 << 10));     // 64 KB
  unsigned long long* adjbits =
      (unsigned long long*)(ws + (6 << 20) + (128 << 10));  // 512 KB

  gemm_xw<<<dim3(N_NODES / 64, OUT_DIM / 64), 256, 0, stream>>>(x, W, Wh);
  compute_s<<<N_NODES / 4, 256, 0, stream>>>(Wh, a, s_src, s_dst);
  transpose_wh<<<dim3(N_NODES / 64, OUT_DIM / 64), 256, 0, stream>>>(Wh, WhT);
  pack_adj<<<(N_NODES * (N_NODES / 64)) / 4, 256, 0, stream>>>(adj, adjbits);
  attn_mfma<<<dim3(N_NODES / 16, HEADS), 256, 0, stream>>>(
      WhT, (const unsigned char*)adjbits, s_src, s_dst, out);
}

// Round 3
// 80.420 us; speedup vs baseline: 2.7470x; 1.3185x over previous
//
#include <hip/hip_runtime.h>
#include <hip/hip_bf16.h>

#define N_NODES 2048
#define IN_DIM 512
#define OUT_DIM 512
#define HEADS 8
#define HEAD_DIM 64
#define NEG_SLOPE 0.2f

typedef float f32x4 __attribute__((ext_vector_type(4)));
typedef short bf16x8 __attribute__((ext_vector_type(8)));

// ---------------------------------------------------------------------------
// Kernel 1: Wh = x @ W   (2048x512 @ 512x512, f32)
// ---------------------------------------------------------------------------
__global__ __launch_bounds__(256) void gemm_xw(
    const float* __restrict__ X, const float* __restrict__ W,
    float* __restrict__ Wh) {
  __shared__ float As[16][68];
  __shared__ float Bs[16][64];

  const int t = threadIdx.x;
  const int tx = t & 15, ty = t >> 4;
  const int bm = blockIdx.x * 64;
  const int bn = blockIdx.y * 64;

  float c[4][4] = {};

  for (int k0 = 0; k0 < IN_DIM; k0 += 16) {
    {
      const int row = t >> 2, kq = (t & 3) * 4;
      const float4 v = *(const float4*)&X[(bm + row) * IN_DIM + k0 + kq];
      As[kq + 0][row] = v.x;
      As[kq + 1][row] = v.y;
      As[kq + 2][row] = v.z;
      As[kq + 3][row] = v.w;
    }
    {
      const int flat = t * 4;
      const int kk = flat >> 6, nn = flat & 63;
      *(float4*)&Bs[kk][nn] = *(const float4*)&W[(k0 + kk) * OUT_DIM + bn + nn];
    }
    __syncthreads();
#pragma unroll
    for (int k = 0; k < 16; ++k) {
      const float4 av = *(const float4*)&As[k][ty * 4];
      const float4 bv = *(const float4*)&Bs[k][tx * 4];
      const float am[4] = {av.x, av.y, av.z, av.w};
      const float bb[4] = {bv.x, bv.y, bv.z, bv.w};
#pragma unroll
      for (int mm = 0; mm < 4; ++mm)
#pragma unroll
        for (int nn = 0; nn < 4; ++nn) c[mm][nn] += am[mm] * bb[nn];
    }
    __syncthreads();
  }

#pragma unroll
  for (int mm = 0; mm < 4; ++mm) {
    float4 v = make_float4(c[mm][0], c[mm][1], c[mm][2], c[mm][3]);
    *(float4*)&Wh[(bm + ty * 4 + mm) * OUT_DIM + bn + tx * 4] = v;
  }
}

// ---------------------------------------------------------------------------
// Kernel 2: s_src[h][n], s_dst[h][n] from Wh rows
// ---------------------------------------------------------------------------
__global__ __launch_bounds__(256) void compute_s(
    const float* __restrict__ Wh, const float* __restrict__ a,
    float* __restrict__ s_src, float* __restrict__ s_dst) {
  const int lane = threadIdx.x & 63;
  const int w = threadIdx.x >> 6;
  const int n = blockIdx.x * 4 + w;
  const float asrc = a[lane];
  const float adst = a[64 + lane];
#pragma unroll
  for (int h = 0; h < HEADS; ++h) {
    const float v = Wh[n * OUT_DIM + h * HEAD_DIM + lane];
    float r1 = v * asrc, r2 = v * adst;
#pragma unroll
    for (int off = 32; off; off >>= 1) {
      r1 += __shfl_xor(r1, off);
      r2 += __shfl_xor(r2, off);
    }
    if (lane == 0) {
      s_src[h * N_NODES + n] = r1;
      s_dst[h * N_NODES + n] = r2;
    }
  }
}

// ---------------------------------------------------------------------------
// Kernel 3: WhT[od][n] = bf16(Wh[n][od])  (512 x 2048 bf16)
// ---------------------------------------------------------------------------
__global__ __launch_bounds__(256) void transpose_wh(
    const float* __restrict__ Wh, __hip_bfloat16* __restrict__ WhT) {
  __shared__ float tile[64][65];
  const int t = threadIdx.x;
  const int n0 = blockIdx.x * 64;
  const int od0 = blockIdx.y * 64;
#pragma unroll
  for (int rr = 0; rr < 16; ++rr) {
    const int nl = rr * 4 + (t >> 6);
    tile[nl][t & 63] = Wh[(size_t)(n0 + nl) * OUT_DIM + od0 + (t & 63)];
  }
  __syncthreads();
#pragma unroll
  for (int rr = 0; rr < 16; ++rr) {
    const int odl = rr * 4 + (t >> 6);
    WhT[(size_t)(od0 + odl) * N_NODES + n0 + (t & 63)] =
        __float2bfloat16(tile[t & 63][odl]);
  }
}

// ---------------------------------------------------------------------------
// Kernel 4: pack adj int32 -> bitmask. adjbits[row][grp] = 64 j-bits.
// ---------------------------------------------------------------------------
__global__ __launch_bounds__(256) void pack_adj(
    const int* __restrict__ adj, unsigned long long* __restrict__ adjbits) {
  const int t = threadIdx.x;
  const int lane = t & 63;
  const int w = t >> 6;
  const int g = blockIdx.x * 4 + w;
  const int rowi = g >> 5;
  const int grp = g & 31;
  const int m = adj[(size_t)rowi * N_NODES + grp * 64 + lane];
  const unsigned long long mask = __ballot(m > 0);
  if (lane == 0) adjbits[(size_t)rowi * 32 + grp] = mask;
}

// ---------------------------------------------------------------------------
// Kernel 5: fused masked softmax + P @ Wh via MFMA, LDS fragment staging.
// grid = (N/32, HEADS), 256 threads = 4 waves; waves split j into quarters.
// Per 64-j tile: stage WhT 64od x 64j into LDS pre-permuted to MFMA B-fragment
// order (ds_read_b128 at lane*16, conflict-free). A (P) generated in-register.
// 32 i-rows/block: 2 m-tiles reuse every B fragment. Global staging loads are
// software-pipelined one tile ahead.
// ---------------------------------------------------------------------------
__global__ __launch_bounds__(256) void attn_mfma(
    const __hip_bfloat16* __restrict__ WhT,
    const unsigned char* __restrict__ adjbits,
    const float* __restrict__ s_src, const float* __restrict__ s_dst,
    float* __restrict__ out) {
  __shared__ short bstage[4][8][64][8];  // [wave][slot][pos][8 bf16] = 32 KB
  __shared__ float acc_lds[4][32][68];   // 34.8 KB
  __shared__ float den_lds[4][32];

  const int t = threadIdx.x;
  const int lane = t & 63;
  const int w = t >> 6;
  const int h = blockIdx.y;
  const int i0 = blockIdx.x * 32;
  const int row = lane & 15;   // A row / B col / C col
  const int kgrp = lane >> 4;  // k-slice group

  // staging lane decomposition: od = c*8 + s_od, j-chunk = s_jc (8 bf16)
  const int s_od = lane >> 3;
  const int s_jc = lane & 7;

  float si[2];
  si[0] = s_src[h * N_NODES + i0 + row];
  si[1] = s_src[h * N_NODES + i0 + 16 + row];
  const unsigned char* __restrict__ ab0 =
      adjbits + (size_t)(i0 + row) * (N_NODES / 8);
  const unsigned char* __restrict__ ab1 =
      adjbits + (size_t)(i0 + 16 + row) * (N_NODES / 8);

  f32x4 acc[2][4] = {};
  float den[2] = {0.f, 0.f};

  // prologue: load first tile (tt=0) for this wave
  bf16x8 ld[8];
  {
    const int j0 = w * 512;
#pragma unroll
    for (int c = 0; c < 8; ++c)
      ld[c] = *(const bf16x8*)&WhT[(size_t)(h * 64 + c * 8 + s_od) * N_NODES +
                                   j0 + s_jc * 8];
  }

  for (int tt = 0; tt < 8; ++tt) {
    const int j0 = w * 512 + tt * 64;

    // ---- p-gen (VALU) — overlaps in-flight global loads ----
    bf16x8 afrag[2][2];
#pragma unroll
    for (int ks = 0; ks < 2; ++ks) {
      const int jj = j0 + ks * 32 + kgrp * 8;
      const float4 sj0 = *(const float4*)&s_dst[h * N_NODES + jj];
      const float4 sj1 = *(const float4*)&s_dst[h * N_NODES + jj + 4];
      const float sjs[8] = {sj0.x, sj0.y, sj0.z, sj0.w,
                            sj1.x, sj1.y, sj1.z, sj1.w};
      const unsigned int mb[2] = {ab0[jj >> 3], ab1[jj >> 3]};
#pragma unroll
      for (int mt = 0; mt < 2; ++mt) {
#pragma unroll
        for (int u = 0; u < 8; ++u) {
          float e = si[mt] + sjs[u];
          e = (e >= 0.f) ? e : NEG_SLOPE * e;
          const float p = ((mb[mt] >> u) & 1u) ? __expf(e) : 0.f;
          den[mt] += p;
          __hip_bfloat16 b = __float2bfloat16(p);
          afrag[mt][ks][u] = *reinterpret_cast<const short*>(&b);
        }
      }
    }

    // ---- write current tile to LDS in fragment order ----
#pragma unroll
    for (int c = 0; c < 8; ++c) {
      const int slot = (c >> 1) * 2 + (s_jc >> 2);
      const int pos = (s_jc & 3) * 16 + (c & 1) * 8 + s_od;
      *(bf16x8*)&bstage[w][slot][pos][0] = ld[c];
    }

    // ---- prefetch next tile ----
    if (tt < 7) {
      const int j1 = j0 + 64;
#pragma unroll
      for (int c = 0; c < 8; ++c)
        ld[c] = *(const bf16x8*)&WhT[(size_t)(h * 64 + c * 8 + s_od) * N_NODES +
                                     j1 + s_jc * 8];
    }

    // ---- fragment reads + MFMA (same-wave DS ordering, no barrier) ----
#pragma unroll
    for (int nt = 0; nt < 4; ++nt) {
      const bf16x8 b0 = *(const bf16x8*)&bstage[w][nt * 2 + 0][lane][0];
      const bf16x8 b1 = *(const bf16x8*)&bstage[w][nt * 2 + 1][lane][0];
      acc[0][nt] =
          __builtin_amdgcn_mfma_f32_16x16x32_bf16(afrag[0][0], b0, acc[0][nt], 0, 0, 0);
      acc[1][nt] =
          __builtin_amdgcn_mfma_f32_16x16x32_bf16(afrag[1][0], b0, acc[1][nt], 0, 0, 0);
      acc[0][nt] =
          __builtin_amdgcn_mfma_f32_16x16x32_bf16(afrag[0][1], b1, acc[0][nt], 0, 0, 0);
      acc[1][nt] =
          __builtin_amdgcn_mfma_f32_16x16x32_bf16(afrag[1][1], b1, acc[1][nt], 0, 0, 0);
    }
  }

  // ---- per-wave partials to LDS; C layout col=lane&15, row=kgrp*4+reg ----
#pragma unroll
  for (int mt = 0; mt < 2; ++mt) {
#pragma unroll
    for (int nt = 0; nt < 4; ++nt)
#pragma unroll
      for (int r = 0; r < 4; ++r)
        acc_lds[w][mt * 16 + kgrp * 4 + r][nt * 16 + row] = acc[mt][nt][r];
    float d2 = den[mt];
    d2 += __shfl_xor(d2, 16);
    d2 += __shfl_xor(d2, 32);
    if (lane < 16) den_lds[w][mt * 16 + lane] = d2;
  }
  __syncthreads();

  // ---- cross-wave reduce + normalize + store ----
  const int d = t & 63;
  const int m0 = t >> 6;
#pragma unroll
  for (int rr = 0; rr < 8; ++rr) {
    const int m = rr * 4 + m0;
    const float v = acc_lds[0][m][d] + acc_lds[1][m][d] + acc_lds[2][m][d] +
                    acc_lds[3][m][d];
    const float dd =
        den_lds[0][m] + den_lds[1][m] + den_lds[2][m] + den_lds[3][m];
    out[(size_t)(i0 + m) * OUT_DIM + h * HEAD_DIM + d] = v / dd;
  }
}

// ---------------------------------------------------------------------------
extern "C" void kernel_launch(void* const* d_in, const int* in_sizes, int n_in,
                              void* d_out, int out_size, void* d_ws,
                              size_t ws_size, hipStream_t stream) {
  const float* x = (const float*)d_in[0];
  const int* adj = (const int*)d_in[1];
  const float* W = (const float*)d_in[2];
  const float* a = (const float*)d_in[3];
  float* out = (float*)d_out;

  char* ws = (char*)d_ws;
  float* Wh = (float*)ws;                                   // 4 MB
  __hip_bfloat16* WhT = (__hip_bfloat16*)(ws + (4 << 20));  // 2 MB
  float* s_src = (float*)(ws + (6 << 20));                  // 64 KB
  float* s_dst = (float*)(ws + (6 << 20) + (64 << 10));     // 64 KB
  unsigned long long* adjbits =
      (unsigned long long*)(ws + (6 << 20) + (128 << 10));  // 512 KB

  gemm_xw<<<dim3(N_NODES / 64, OUT_DIM / 64), 256, 0, stream>>>(x, W, Wh);
  compute_s<<<N_NODES / 4, 256, 0, stream>>>(Wh, a, s_src, s_dst);
  transpose_wh<<<dim3(N_NODES / 64, OUT_DIM / 64), 256, 0, stream>>>(Wh, WhT);
  pack_adj<<<(N_NODES * (N_NODES / 64)) / 4, 256, 0, stream>>>(adj, adjbits);
  attn_mfma<<<dim3(N_NODES / 32, HEADS), 256, 0, stream>>>(
      WhT, (const unsigned char*)adjbits, s_src, s_dst, out);
}

// Round 4
// 59.040 us; speedup vs baseline: 3.7418x; 1.3621x over previous
//
#include <hip/hip_runtime.h>
#include <hip/hip_bf16.h>

#define NN 2048
#define KD 512  // IN_DIM
#define ODIM 512
#define NHEAD 8
#define HD 64
#define NEG 0.2f

typedef float f32x4 __attribute__((ext_vector_type(4)));
typedef short bf16x8 __attribute__((ext_vector_type(8)));
typedef short bf16x4 __attribute__((ext_vector_type(4)));
typedef unsigned long long u64;

__device__ __forceinline__ short tob(float f) {
  __hip_bfloat16 h = __float2bfloat16(f);
  return *reinterpret_cast<short*>(&h);
}

// ---------------------------------------------------------------------------
// cast_wt: WTb[od][k] = bf16(W[k][od])  (512x512)
// ---------------------------------------------------------------------------
__global__ __launch_bounds__(256) void cast_wt(const float* __restrict__ W,
                                               __hip_bfloat16* __restrict__ WTb) {
  __shared__ float tile[64][68];
  const int t = threadIdx.x;
  const int k0 = blockIdx.x * 64, od0 = blockIdx.y * 64;
#pragma unroll
  for (int r = 0; r < 4; ++r) {
    const int flat = r * 256 + t;
    const int kk = flat >> 4, oq = (flat & 15) * 4;
    const float4 v = *(const float4*)&W[(size_t)(k0 + kk) * ODIM + od0 + oq];
    tile[kk][oq] = v.x;
    tile[kk][oq + 1] = v.y;
    tile[kk][oq + 2] = v.z;
    tile[kk][oq + 3] = v.w;
  }
  __syncthreads();
#pragma unroll
  for (int r = 0; r < 2; ++r) {
    const int flat = r * 256 + t;
    const int od = flat >> 3, kq = (flat & 7) * 8;
    bf16x8 o;
#pragma unroll
    for (int u = 0; u < 8; ++u) o[u] = tob(tile[kq + u][od]);
    *(bf16x8*)&WTb[(size_t)(od0 + od) * KD + k0 + kq] = o;
  }
}

// ---------------------------------------------------------------------------
// pack_adj: 16 j-bits per thread, 64B contiguous loads per thread.
// bits[row*128 + g] covers j = g*16 .. g*16+15 (little-endian u16).
// ---------------------------------------------------------------------------
__global__ __launch_bounds__(256) void pack_adj(const int* __restrict__ adj,
                                                unsigned short* __restrict__ bits) {
  const int T = blockIdx.x * 256 + threadIdx.x;  // 0..262143
  const int row = T >> 7, g = T & 127;
  const int* p = adj + (size_t)row * NN + g * 16;
  unsigned int m = 0;
#pragma unroll
  for (int q = 0; q < 4; ++q) {
    const int4 v = *(const int4*)&p[q * 4];
    m |= (v.x > 0 ? 1u : 0u) << (q * 4);
    m |= (v.y > 0 ? 2u : 0u) << (q * 4);
    m |= (v.z > 0 ? 4u : 0u) << (q * 4);
    m |= (v.w > 0 ? 8u : 0u) << (q * 4);
  }
  bits[T] = (unsigned short)m;
}

// ---------------------------------------------------------------------------
// gemm_fused: Wh-tile = x @ W (bf16 MFMA); epilogue writes WhT bf16
// (transposed), plus exp tables: esrcp[h][n] = (exp(s_src), exp(0.2 s_src)),
// edstp[h][n] = packed bf16 (exp(s_dst) | exp(0.2 s_dst) << 16).
// grid (32, 8): 64 node-rows x one head (64 od) per block. 4 waves split m.
// ---------------------------------------------------------------------------
__global__ __launch_bounds__(256) void gemm_fused(
    const float* __restrict__ X, const __hip_bfloat16* __restrict__ WTb,
    const float* __restrict__ a, __hip_bfloat16* __restrict__ WhT,
    float2* __restrict__ esrcp, unsigned int* __restrict__ edstp) {
  __shared__ short As[64][72];
  __shared__ short Bs[64][72];
  const int t = threadIdx.x;
  const int lane = t & 63, w = t >> 6;
  const int col = lane & 15, kgrp = lane >> 4;
  const int bm = blockIdx.x * 64;
  const int h = blockIdx.y;

  const int am = t >> 2, ak = (t & 3) * 16;  // A staging: row, k-base (16 k)
  const int bn = t >> 2, bk = (t & 3) * 16;  // B staging

  float4 xa[4];
  bf16x8 wb[2];
#pragma unroll
  for (int q = 0; q < 4; ++q)
    xa[q] = *(const float4*)&X[(size_t)(bm + am) * KD + ak + q * 4];
#pragma unroll
  for (int q = 0; q < 2; ++q)
    wb[q] = *(const bf16x8*)&WTb[(size_t)(h * 64 + bn) * KD + bk + q * 8];

  f32x4 acc[4] = {};

  for (int k0 = 0; k0 < KD; k0 += 64) {
    // write staged regs to LDS (cvt x to bf16)
#pragma unroll
    for (int q = 0; q < 2; ++q) {
      bf16x8 o;
#pragma unroll
      for (int u = 0; u < 4; ++u) {
        o[u] = tob(((const float*)&xa[q * 2])[u]);
        o[u + 4] = tob(((const float*)&xa[q * 2 + 1])[u]);
      }
      *(bf16x8*)&As[am][ak + q * 8] = o;
      *(bf16x8*)&Bs[bn][bk + q * 8] = wb[q];
    }
    __syncthreads();
    if (k0 + 64 < KD) {
      const int k1 = k0 + 64;
#pragma unroll
      for (int q = 0; q < 4; ++q)
        xa[q] = *(const float4*)&X[(size_t)(bm + am) * KD + k1 + ak + q * 4];
#pragma unroll
      for (int q = 0; q < 2; ++q)
        wb[q] = *(const bf16x8*)&WTb[(size_t)(h * 64 + bn) * KD + k1 + bk + q * 8];
    }
#pragma unroll
    for (int ks = 0; ks < 2; ++ks) {
      const bf16x8 af = *(const bf16x8*)&As[w * 16 + col][ks * 32 + kgrp * 8];
#pragma unroll
      for (int nt = 0; nt < 4; ++nt) {
        const bf16x8 bf = *(const bf16x8*)&Bs[nt * 16 + col][ks * 32 + kgrp * 8];
        acc[nt] = __builtin_amdgcn_mfma_f32_16x16x32_bf16(af, bf, acc[nt], 0, 0, 0);
      }
    }
    __syncthreads();
  }

  // ---- epilogue ----
  float asv[4], adv[4];
#pragma unroll
  for (int nt = 0; nt < 4; ++nt) {
    asv[nt] = a[nt * 16 + col];
    adv[nt] = a[64 + nt * 16 + col];
  }
  const int mbase = bm + w * 16 + kgrp * 4;
  float ps[4], pd[4];
#pragma unroll
  for (int r = 0; r < 4; ++r) {
    float s1 = 0.f, s2 = 0.f;
#pragma unroll
    for (int nt = 0; nt < 4; ++nt) {
      s1 += acc[nt][r] * asv[nt];
      s2 += acc[nt][r] * adv[nt];
    }
    ps[r] = s1;
    pd[r] = s2;
  }
#pragma unroll
  for (int off = 1; off <= 8; off <<= 1) {
#pragma unroll
    for (int r = 0; r < 4; ++r) {
      ps[r] += __shfl_xor(ps[r], off);
      pd[r] += __shfl_xor(pd[r], off);
    }
  }
  // WhT[od][m] bf16 stores (4 consecutive m per lane)
#pragma unroll
  for (int nt = 0; nt < 4; ++nt) {
    bf16x4 o;
#pragma unroll
    for (int r = 0; r < 4; ++r) o[r] = tob(acc[nt][r]);
    *(bf16x4*)&WhT[(size_t)(h * 64 + nt * 16 + col) * NN + mbase] = o;
  }
  if (col == 0) {
#pragma unroll
    for (int r = 0; r < 4; ++r) {
      const int n = mbase + r;
      esrcp[h * NN + n] = make_float2(__expf(ps[r]), __expf(NEG * ps[r]));
      const unsigned int lo = (unsigned int)(unsigned short)tob(__expf(pd[r]));
      const unsigned int hi = (unsigned int)(unsigned short)tob(__expf(NEG * pd[r]));
      edstp[h * NN + n] = (hi << 16) | lo;
    }
  }
}

// ---------------------------------------------------------------------------
// attn_mfma: p = mask ? max(Ai*Bj, Ci*Dj) : 0 (== exp(leakyrelu(si+sj)));
// P @ Wh via MFMA with fragment-permuted LDS staging; denominator via
// ones-vector MFMA. grid (128, 8); 4 waves split j; 16 i-rows per block.
// ---------------------------------------------------------------------------
__global__ __launch_bounds__(256, 3) void attn_mfma(
    const __hip_bfloat16* __restrict__ WhT,
    const unsigned char* __restrict__ adjbits, const float2* __restrict__ esrcp,
    const unsigned int* __restrict__ edstp, float* __restrict__ out) {
  __shared__ __align__(16) char lds[32768];  // per-wave 8KB: bstage, then acc
  const int t = threadIdx.x;
  const int lane = t & 63, w = t >> 6;
  const int col = lane & 15, kgrp = lane >> 4;
  const int h = blockIdx.y;
  const int i0 = blockIdx.x * 16;

  char* ldsw = lds + w * 8192;
  const int s_od = lane >> 3, s_jc = lane & 7;

  const float2 eAC = esrcp[h * NN + i0 + col];
  const float Ai = eAC.x, Ci = eAC.y;
  const unsigned char* abrow = adjbits + (size_t)(i0 + col) * (NN / 8);

  bf16x8 ones;
#pragma unroll
  for (int u = 0; u < 8; ++u) ones[u] = (short)0x3F80;

  f32x4 acc[4] = {};
  f32x4 accd = {};

  const int jbase = w * 512;
  bf16x8 ld[8];
  uint4 bd[4];
  u64 aw;
#pragma unroll
  for (int c = 0; c < 8; ++c)
    ld[c] = *(const bf16x8*)&WhT[(size_t)(h * 64 + c * 8 + s_od) * NN + jbase +
                                 s_jc * 8];
#pragma unroll
  for (int ks = 0; ks < 2; ++ks) {
    const int jj = jbase + ks * 32 + kgrp * 8;
    bd[ks * 2] = *(const uint4*)&edstp[h * NN + jj];
    bd[ks * 2 + 1] = *(const uint4*)&edstp[h * NN + jj + 4];
  }
  aw = *(const u64*)(abrow + (jbase >> 3));

  for (int tt = 0; tt < 8; ++tt) {
    const int j0 = jbase + tt * 64;
    // LDS write in MFMA-fragment order
#pragma unroll
    for (int c = 0; c < 8; ++c) {
      const int slot = (c >> 1) * 2 + (s_jc >> 2);
      const int pos = (s_jc & 3) * 16 + (c & 1) * 8 + s_od;
      *(bf16x8*)(ldsw + (slot * 64 + pos) * 16) = ld[c];
    }
    const uint4 bc0 = bd[0], bc1 = bd[1], bc2 = bd[2], bc3 = bd[3];
    const u64 awc = aw;
    if (tt < 7) {  // prefetch next tile
      const int j1 = j0 + 64;
#pragma unroll
      for (int c = 0; c < 8; ++c)
        ld[c] = *(const bf16x8*)&WhT[(size_t)(h * 64 + c * 8 + s_od) * NN + j1 +
                                     s_jc * 8];
#pragma unroll
      for (int ks = 0; ks < 2; ++ks) {
        const int jj = j1 + ks * 32 + kgrp * 8;
        bd[ks * 2] = *(const uint4*)&edstp[h * NN + jj];
        bd[ks * 2 + 1] = *(const uint4*)&edstp[h * NN + jj + 4];
      }
      aw = *(const u64*)(abrow + (j1 >> 3));
    }
    // p-gen: no transcendentals
    bf16x8 af[2];
#pragma unroll
    for (int ks = 0; ks < 2; ++ks) {
      const unsigned int mb = (unsigned int)(awc >> ((ks * 4 + kgrp) * 8)) & 0xffu;
      const uint4 q0 = ks ? bc2 : bc0;
      const uint4 q1 = ks ? bc3 : bc1;
      const unsigned int uw[8] = {q0.x, q0.y, q0.z, q0.w,
                                  q1.x, q1.y, q1.z, q1.w};
#pragma unroll
      for (int u = 0; u < 8; ++u) {
        const float B = __uint_as_float(uw[u] << 16);
        const float D = __uint_as_float(uw[u] & 0xffff0000u);
        float p = fmaxf(Ai * B, Ci * D);
        p = ((mb >> u) & 1u) ? p : 0.f;
        af[ks][u] = tob(p);
      }
    }
    // MFMAs: denominator (ones) + 4 od-tiles
    accd = __builtin_amdgcn_mfma_f32_16x16x32_bf16(af[0], ones, accd, 0, 0, 0);
    accd = __builtin_amdgcn_mfma_f32_16x16x32_bf16(af[1], ones, accd, 0, 0, 0);
#pragma unroll
    for (int nt = 0; nt < 4; ++nt) {
      const bf16x8 b0 = *(const bf16x8*)(ldsw + ((nt * 2 + 0) * 64 + lane) * 16);
      const bf16x8 b1 = *(const bf16x8*)(ldsw + ((nt * 2 + 1) * 64 + lane) * 16);
      acc[nt] = __builtin_amdgcn_mfma_f32_16x16x32_bf16(af[0], b0, acc[nt], 0, 0, 0);
      acc[nt] = __builtin_amdgcn_mfma_f32_16x16x32_bf16(af[1], b1, acc[nt], 0, 0, 0);
    }
  }

  // per-wave partials into own 8KB region (aliases bstage; same-wave in-order)
  float* accw = (float*)ldsw;          // [16][68]
  float* denw = accw + 16 * 68;        // [16]
#pragma unroll
  for (int nt = 0; nt < 4; ++nt)
#pragma unroll
    for (int r = 0; r < 4; ++r)
      accw[(kgrp * 4 + r) * 68 + nt * 16 + col] = acc[nt][r];
  if (col == 0) {
#pragma unroll
    for (int r = 0; r < 4; ++r) denw[kgrp * 4 + r] = accd[r];
  }
  __syncthreads();

  const int d = t & 63, mq = t >> 6;
#pragma unroll
  for (int rr = 0; rr < 4; ++rr) {
    const int m = rr * 4 + mq;
    float v = 0.f, dd = 0.f;
#pragma unroll
    for (int w2 = 0; w2 < 4; ++w2) {
      const float* aw2 = (const float*)(lds + w2 * 8192);
      v += aw2[m * 68 + d];
      dd += aw2[16 * 68 + m];
    }
    out[(size_t)(i0 + m) * ODIM + h * HD + d] = v / dd;
  }
}

// ---------------------------------------------------------------------------
extern "C" void kernel_launch(void* const* d_in, const int* in_sizes, int n_in,
                              void* d_out, int out_size, void* d_ws,
                              size_t ws_size, hipStream_t stream) {
  const float* x = (const float*)d_in[0];
  const int* adj = (const int*)d_in[1];
  const float* W = (const float*)d_in[2];
  const float* a = (const float*)d_in[3];
  float* out = (float*)d_out;

  char* ws = (char*)d_ws;
  __hip_bfloat16* WhT = (__hip_bfloat16*)ws;                    // 2 MB
  __hip_bfloat16* WTb = (__hip_bfloat16*)(ws + (2 << 20));      // 512 KB
  unsigned short* bits =
      (unsigned short*)(ws + (2 << 20) + (512 << 10));          // 512 KB
  float2* esrcp = (float2*)(ws + (3 << 20));                    // 128 KB
  unsigned int* edstp = (unsigned int*)(ws + (3 << 20) + (128 << 10));  // 64 KB

  cast_wt<<<dim3(8, 8), 256, 0, stream>>>(W, WTb);
  pack_adj<<<1024, 256, 0, stream>>>(adj, bits);
  gemm_fused<<<dim3(32, 8), 256, 0, stream>>>(x, WTb, a, WhT, esrcp, edstp);
  attn_mfma<<<dim3(128, 8), 256, 0, stream>>>(
      WhT, (const unsigned char*)bits, esrcp, edstp, out);
}

// Round 5
// 39.781 us; speedup vs baseline: 5.5532x; 1.4841x over previous
//
#include <hip/hip_runtime.h>
#include <hip/hip_bf16.h>

#define NN 2048
#define KD 512  // IN_DIM
#define ODIM 512
#define NHEAD 8
#define HD 64
#define NEG 0.2f

typedef float f32x4 __attribute__((ext_vector_type(4)));
typedef short bf16x8 __attribute__((ext_vector_type(8)));
typedef short bf16x4 __attribute__((ext_vector_type(4)));
typedef unsigned long long u64;

__device__ __forceinline__ short tob(float f) {
  __hip_bfloat16 h = __float2bfloat16(f);
  return *reinterpret_cast<short*>(&h);
}

// ---------------------------------------------------------------------------
// cast_wt: WTb[od][k] = bf16(W[k][od])  (512x512)
// ---------------------------------------------------------------------------
__global__ __launch_bounds__(256) void cast_wt(const float* __restrict__ W,
                                               __hip_bfloat16* __restrict__ WTb) {
  __shared__ float tile[64][68];
  const int t = threadIdx.x;
  const int k0 = blockIdx.x * 64, od0 = blockIdx.y * 64;
#pragma unroll
  for (int r = 0; r < 4; ++r) {
    const int flat = r * 256 + t;
    const int kk = flat >> 4, oq = (flat & 15) * 4;
    const float4 v = *(const float4*)&W[(size_t)(k0 + kk) * ODIM + od0 + oq];
    tile[kk][oq] = v.x;
    tile[kk][oq + 1] = v.y;
    tile[kk][oq + 2] = v.z;
    tile[kk][oq + 3] = v.w;
  }
  __syncthreads();
#pragma unroll
  for (int r = 0; r < 2; ++r) {
    const int flat = r * 256 + t;
    const int od = flat >> 3, kq = (flat & 7) * 8;
    bf16x8 o;
#pragma unroll
    for (int u = 0; u < 8; ++u) o[u] = tob(tile[kq + u][od]);
    *(bf16x8*)&WTb[(size_t)(od0 + od) * KD + k0 + kq] = o;
  }
}

// ---------------------------------------------------------------------------
// pack_adj: 16 j-bits per thread, 64B contiguous loads per thread.
// ---------------------------------------------------------------------------
__global__ __launch_bounds__(256) void pack_adj(const int* __restrict__ adj,
                                                unsigned short* __restrict__ bits) {
  const int T = blockIdx.x * 256 + threadIdx.x;
  const int row = T >> 7, g = T & 127;
  const int* p = adj + (size_t)row * NN + g * 16;
  unsigned int m = 0;
#pragma unroll
  for (int q = 0; q < 4; ++q) {
    const int4 v = *(const int4*)&p[q * 4];
    m |= (v.x > 0 ? 1u : 0u) << (q * 4);
    m |= (v.y > 0 ? 2u : 0u) << (q * 4);
    m |= (v.z > 0 ? 4u : 0u) << (q * 4);
    m |= (v.w > 0 ? 8u : 0u) << (q * 4);
  }
  bits[T] = (unsigned short)m;
}

// ---------------------------------------------------------------------------
// gemm_fused: Wh = x @ W (bf16 MFMA). Epilogue stores Wh in MFMA-B-fragment
// order: WhF[(h*32+jt)*4096 + slot*512 + lane*8 + u] (shorts), where
// slot = nt*2+ks holds Wh[j = jt*64 + ks*32 + (lane>>4)*8 + u]
//                       [od = h*64 + nt*16 + (lane&15)].
// Also emits exp tables esrcp (f32 pair) / edstp (packed bf16 pair).
// grid (32, 8): 64 node-rows x one head per block; jt = blockIdx.x.
// ---------------------------------------------------------------------------
__global__ __launch_bounds__(256) void gemm_fused(
    const float* __restrict__ X, const __hip_bfloat16* __restrict__ WTb,
    const float* __restrict__ a, short* __restrict__ WhF,
    float2* __restrict__ esrcp, unsigned int* __restrict__ edstp) {
  __shared__ short As[64][72];
  __shared__ short Bs[64][72];
  const int t = threadIdx.x;
  const int lane = t & 63, w = t >> 6;
  const int col = lane & 15, kgrp = lane >> 4;
  const int bm = blockIdx.x * 64;
  const int h = blockIdx.y;

  const int am = t >> 2, ak = (t & 3) * 16;
  const int bn = t >> 2, bk = (t & 3) * 16;

  float4 xa[4];
  bf16x8 wb[2];
#pragma unroll
  for (int q = 0; q < 4; ++q)
    xa[q] = *(const float4*)&X[(size_t)(bm + am) * KD + ak + q * 4];
#pragma unroll
  for (int q = 0; q < 2; ++q)
    wb[q] = *(const bf16x8*)&WTb[(size_t)(h * 64 + bn) * KD + bk + q * 8];

  f32x4 acc[4] = {};

  for (int k0 = 0; k0 < KD; k0 += 64) {
#pragma unroll
    for (int q = 0; q < 2; ++q) {
      bf16x8 o;
#pragma unroll
      for (int u = 0; u < 4; ++u) {
        o[u] = tob(((const float*)&xa[q * 2])[u]);
        o[u + 4] = tob(((const float*)&xa[q * 2 + 1])[u]);
      }
      *(bf16x8*)&As[am][ak + q * 8] = o;
      *(bf16x8*)&Bs[bn][bk + q * 8] = wb[q];
    }
    __syncthreads();
    if (k0 + 64 < KD) {
      const int k1 = k0 + 64;
#pragma unroll
      for (int q = 0; q < 4; ++q)
        xa[q] = *(const float4*)&X[(size_t)(bm + am) * KD + k1 + ak + q * 4];
#pragma unroll
      for (int q = 0; q < 2; ++q)
        wb[q] = *(const bf16x8*)&WTb[(size_t)(h * 64 + bn) * KD + k1 + bk + q * 8];
    }
#pragma unroll
    for (int ks = 0; ks < 2; ++ks) {
      const bf16x8 af = *(const bf16x8*)&As[w * 16 + col][ks * 32 + kgrp * 8];
#pragma unroll
      for (int nt = 0; nt < 4; ++nt) {
        const bf16x8 bf = *(const bf16x8*)&Bs[nt * 16 + col][ks * 32 + kgrp * 8];
        acc[nt] = __builtin_amdgcn_mfma_f32_16x16x32_bf16(af, bf, acc[nt], 0, 0, 0);
      }
    }
    __syncthreads();
  }

  // ---- epilogue: s-dots, exp tables, fragment-ordered Wh stores ----
  float asv[4], adv[4];
#pragma unroll
  for (int nt = 0; nt < 4; ++nt) {
    asv[nt] = a[nt * 16 + col];
    adv[nt] = a[64 + nt * 16 + col];
  }
  float ps[4], pd[4];
#pragma unroll
  for (int r = 0; r < 4; ++r) {
    float s1 = 0.f, s2 = 0.f;
#pragma unroll
    for (int nt = 0; nt < 4; ++nt) {
      s1 += acc[nt][r] * asv[nt];
      s2 += acc[nt][r] * adv[nt];
    }
    ps[r] = s1;
    pd[r] = s2;
  }
#pragma unroll
  for (int off = 1; off <= 8; off <<= 1) {
#pragma unroll
    for (int r = 0; r < 4; ++r) {
      ps[r] += __shfl_xor(ps[r], off);
      pd[r] += __shfl_xor(pd[r], off);
    }
  }
  // fragment stores: this thread owns rows m = bm + w*16 + kgrp*4 + r
  {
    const size_t tbase = ((size_t)h * 32 + blockIdx.x) * 4096;
    const int lp = ((w & 1) * 2 + (kgrp >> 1)) * 16 + col;  // lane within frag
    const int u0 = (kgrp & 1) * 4;
    const int slot_ks = w >> 1;
#pragma unroll
    for (int nt = 0; nt < 4; ++nt) {
      bf16x4 o;
#pragma unroll
      for (int r = 0; r < 4; ++r) o[r] = tob(acc[nt][r]);
      *(bf16x4*)&WhF[tbase + (size_t)(nt * 2 + slot_ks) * 512 + lp * 8 + u0] = o;
    }
  }
  if (col == 0) {
    const int mbase = bm + w * 16 + kgrp * 4;
#pragma unroll
    for (int r = 0; r < 4; ++r) {
      const int n = mbase + r;
      esrcp[h * NN + n] = make_float2(__expf(ps[r]), __expf(NEG * ps[r]));
      const unsigned int lo = (unsigned int)(unsigned short)tob(__expf(pd[r]));
      const unsigned int hi = (unsigned int)(unsigned short)tob(__expf(NEG * pd[r]));
      edstp[h * NN + n] = (hi << 16) | lo;
    }
  }
}

// ---------------------------------------------------------------------------
// attn_mfma: p = mask ? max(Ai*Bj, Ci*Dj) : 0; P @ Wh via MFMA with
// B-fragments read straight from fragment-ordered WhF (coalesced, L2-hot).
// grid (64, 8): 32 i-rows per block; 4 waves split j into quarters.
// No LDS in the main loop; LDS only for the final cross-wave reduce.
// ---------------------------------------------------------------------------
__global__ __launch_bounds__(256, 2) void attn_mfma(
    const short* __restrict__ WhF, const unsigned char* __restrict__ adjbits,
    const float2* __restrict__ esrcp, const unsigned int* __restrict__ edstp,
    float* __restrict__ out) {
  __shared__ float accw[4][32][68];
  __shared__ float denw[4][32];

  const int t = threadIdx.x;
  const int lane = t & 63, w = t >> 6;
  const int col = lane & 15, kgrp = lane >> 4;
  const int h = blockIdx.y;
  const int i0 = blockIdx.x * 32;

  const float2 e0 = esrcp[h * NN + i0 + col];
  const float2 e1 = esrcp[h * NN + i0 + 16 + col];
  const float A0 = e0.x, C0 = e0.y, A1 = e1.x, C1 = e1.y;
  const unsigned char* ab0 = adjbits + (size_t)(i0 + col) * (NN / 8);
  const unsigned char* ab1 = adjbits + (size_t)(i0 + 16 + col) * (NN / 8);

  bf16x8 ones;
#pragma unroll
  for (int u = 0; u < 8; ++u) ones[u] = (short)0x3F80;

  f32x4 acc[2][4] = {};
  f32x4 accd[2] = {};

  const int jbase = w * 512;
  const short* tb = WhF + ((size_t)h * 32 + w * 8) * 4096;

  // prologue: prefetch tile 0 (B-frags, exp pairs, mask words)
  bf16x8 bc[8];
  uint4 bd[4];
  u64 aw0, aw1;
#pragma unroll
  for (int s = 0; s < 8; ++s) bc[s] = *(const bf16x8*)&tb[s * 512 + lane * 8];
#pragma unroll
  for (int ks = 0; ks < 2; ++ks) {
    const int jj = jbase + ks * 32 + kgrp * 8;
    bd[ks * 2] = *(const uint4*)&edstp[h * NN + jj];
    bd[ks * 2 + 1] = *(const uint4*)&edstp[h * NN + jj + 4];
  }
  aw0 = *(const u64*)(ab0 + (jbase >> 3));
  aw1 = *(const u64*)(ab1 + (jbase >> 3));

#pragma unroll
  for (int tt = 0; tt < 8; ++tt) {
    const int j0 = jbase + tt * 64;
    // prefetch next tile
    bf16x8 bn[8];
    uint4 bdn[4];
    u64 an0 = 0, an1 = 0;
    if (tt < 7) {
      const short* tbn = tb + (size_t)(tt + 1) * 4096;
      const int j1 = j0 + 64;
#pragma unroll
      for (int s = 0; s < 8; ++s)
        bn[s] = *(const bf16x8*)&tbn[s * 512 + lane * 8];
#pragma unroll
      for (int ks = 0; ks < 2; ++ks) {
        const int jj = j1 + ks * 32 + kgrp * 8;
        bdn[ks * 2] = *(const uint4*)&edstp[h * NN + jj];
        bdn[ks * 2 + 1] = *(const uint4*)&edstp[h * NN + jj + 4];
      }
      an0 = *(const u64*)(ab0 + (j1 >> 3));
      an1 = *(const u64*)(ab1 + (j1 >> 3));
    }

    // p-gen (no transcendentals)
    bf16x8 af0[2], af1[2];
#pragma unroll
    for (int ks = 0; ks < 2; ++ks) {
      const unsigned int mb0 =
          (unsigned int)(aw0 >> ((ks * 4 + kgrp) * 8)) & 0xffu;
      const unsigned int mb1 =
          (unsigned int)(aw1 >> ((ks * 4 + kgrp) * 8)) & 0xffu;
      const uint4 q0 = bd[ks * 2], q1 = bd[ks * 2 + 1];
      const unsigned int uw[8] = {q0.x, q0.y, q0.z, q0.w,
                                  q1.x, q1.y, q1.z, q1.w};
#pragma unroll
      for (int u = 0; u < 8; ++u) {
        const float B = __uint_as_float(uw[u] << 16);
        const float D = __uint_as_float(uw[u] & 0xffff0000u);
        float p0 = fmaxf(A0 * B, C0 * D);
        float p1 = fmaxf(A1 * B, C1 * D);
        p0 = ((mb0 >> u) & 1u) ? p0 : 0.f;
        p1 = ((mb1 >> u) & 1u) ? p1 : 0.f;
        af0[ks][u] = tob(p0);
        af1[ks][u] = tob(p1);
      }
    }

    // MFMAs: 4 denominator + 16 od-tiles
    accd[0] = __builtin_amdgcn_mfma_f32_16x16x32_bf16(af0[0], ones, accd[0], 0, 0, 0);
    accd[0] = __builtin_amdgcn_mfma_f32_16x16x32_bf16(af0[1], ones, accd[0], 0, 0, 0);
    accd[1] = __builtin_amdgcn_mfma_f32_16x16x32_bf16(af1[0], ones, accd[1], 0, 0, 0);
    accd[1] = __builtin_amdgcn_mfma_f32_16x16x32_bf16(af1[1], ones, accd[1], 0, 0, 0);
#pragma unroll
    for (int nt = 0; nt < 4; ++nt) {
#pragma unroll
      for (int ks = 0; ks < 2; ++ks) {
        const bf16x8 b = bc[nt * 2 + ks];
        acc[0][nt] = __builtin_amdgcn_mfma_f32_16x16x32_bf16(af0[ks], b, acc[0][nt], 0, 0, 0);
        acc[1][nt] = __builtin_amdgcn_mfma_f32_16x16x32_bf16(af1[ks], b, acc[1][nt], 0, 0, 0);
      }
    }

    // rotate prefetch
    if (tt < 7) {
#pragma unroll
      for (int s = 0; s < 8; ++s) bc[s] = bn[s];
#pragma unroll
      for (int q = 0; q < 4; ++q) bd[q] = bdn[q];
      aw0 = an0;
      aw1 = an1;
    }
  }

  // per-wave partials
#pragma unroll
  for (int mt = 0; mt < 2; ++mt)
#pragma unroll
    for (int nt = 0; nt < 4; ++nt)
#pragma unroll
      for (int r = 0; r < 4; ++r)
        accw[w][mt * 16 + kgrp * 4 + r][nt * 16 + col] = acc[mt][nt][r];
  if (col == 0) {
#pragma unroll
    for (int mt = 0; mt < 2; ++mt)
#pragma unroll
      for (int r = 0; r < 4; ++r)
        denw[w][mt * 16 + kgrp * 4 + r] = accd[mt][r];
  }
  __syncthreads();

  // cross-wave reduce + normalize + store
  const int d = t & 63, mq = t >> 6;
#pragma unroll
  for (int rr = 0; rr < 8; ++rr) {
    const int m = rr * 4 + mq;
    float v = accw[0][m][d] + accw[1][m][d] + accw[2][m][d] + accw[3][m][d];
    float dd = denw[0][m] + denw[1][m] + denw[2][m] + denw[3][m];
    out[(size_t)(i0 + m) * ODIM + h * HD + d] = v / dd;
  }
}

// ---------------------------------------------------------------------------
extern "C" void kernel_launch(void* const* d_in, const int* in_sizes, int n_in,
                              void* d_out, int out_size, void* d_ws,
                              size_t ws_size, hipStream_t stream) {
  const float* x = (const float*)d_in[0];
  const int* adj = (const int*)d_in[1];
  const float* W = (const float*)d_in[2];
  const float* a = (const float*)d_in[3];
  float* out = (float*)d_out;

  char* ws = (char*)d_ws;
  short* WhF = (short*)ws;                                      // 2 MB
  __hip_bfloat16* WTb = (__hip_bfloat16*)(ws + (2 << 20));      // 512 KB
  unsigned short* bits =
      (unsigned short*)(ws + (2 << 20) + (512 << 10));          // 512 KB
  float2* esrcp = (float2*)(ws + (3 << 20));                    // 128 KB
  unsigned int* edstp = (unsigned int*)(ws + (3 << 20) + (128 << 10));  // 64 KB

  cast_wt<<<dim3(8, 8), 256, 0, stream>>>(W, WTb);
  pack_adj<<<1024, 256, 0, stream>>>(adj, bits);
  gemm_fused<<<dim3(32, 8), 256, 0, stream>>>(x, WTb, a, WhF, esrcp, edstp);
  attn_mfma<<<dim3(64, 8), 256, 0, stream>>>(
      WhF, (const unsigned char*)bits, esrcp, edstp, out);
}

// Round 6
// 36.718 us; speedup vs baseline: 6.0165x; 1.0834x over previous
//
#include <hip/hip_runtime.h>
#include <hip/hip_bf16.h>

#define NN 2048
#define KD 512
#define ODIM 512
#define NHEAD 8
#define HD 64
#define NEG 0.2f

typedef float f32x4 __attribute__((ext_vector_type(4)));
typedef short bf16x8 __attribute__((ext_vector_type(8)));
typedef short bf16x4 __attribute__((ext_vector_type(4)));
typedef unsigned long long u64;
typedef unsigned int u32;

__device__ __forceinline__ short tob(float f) {
  __hip_bfloat16 h = __float2bfloat16(f);
  return *reinterpret_cast<short*>(&h);
}

// async global -> LDS, 16 B per lane; LDS dest = uniform base + lane*16
__device__ __forceinline__ void gl_lds16(const void* g, void* l) {
  __builtin_amdgcn_global_load_lds(
      (const __attribute__((address_space(1))) u32*)g,
      (__attribute__((address_space(3))) u32*)l, 16, 0, 0);
}

// ---------------------------------------------------------------------------
// prep: blocks 0..63  -> WTb[od][k] = bf16(W[k][od])
//       blocks 64..   -> pack adj into 16-bit masks
// ---------------------------------------------------------------------------
__global__ __launch_bounds__(256) void prep(const float* __restrict__ W,
                                            const int* __restrict__ adj,
                                            __hip_bfloat16* __restrict__ WTb,
                                            unsigned short* __restrict__ bits) {
  const int b = blockIdx.x;
  const int t = threadIdx.x;
  if (b >= 64) {
    const int T = (b - 64) * 256 + t;
    const int row = T >> 7, g = T & 127;
    const int* p = adj + (size_t)row * NN + g * 16;
    u32 m = 0;
#pragma unroll
    for (int q = 0; q < 4; ++q) {
      const int4 v = *(const int4*)&p[q * 4];
      m |= (v.x > 0 ? 1u : 0u) << (q * 4);
      m |= (v.y > 0 ? 2u : 0u) << (q * 4);
      m |= (v.z > 0 ? 4u : 0u) << (q * 4);
      m |= (v.w > 0 ? 8u : 0u) << (q * 4);
    }
    bits[T] = (unsigned short)m;
    return;
  }
  __shared__ float tile[64][68];
  const int k0 = (b & 7) * 64, od0 = (b >> 3) * 64;
#pragma unroll
  for (int r = 0; r < 4; ++r) {
    const int flat = r * 256 + t;
    const int kk = flat >> 4, oq = (flat & 15) * 4;
    const float4 v = *(const float4*)&W[(size_t)(k0 + kk) * ODIM + od0 + oq];
    tile[kk][oq] = v.x;
    tile[kk][oq + 1] = v.y;
    tile[kk][oq + 2] = v.z;
    tile[kk][oq + 3] = v.w;
  }
  __syncthreads();
#pragma unroll
  for (int r = 0; r < 2; ++r) {
    const int flat = r * 256 + t;
    const int od = flat >> 3, kq = (flat & 7) * 8;
    bf16x8 o;
#pragma unroll
    for (int u = 0; u < 8; ++u) o[u] = tob(tile[kq + u][od]);
    *(bf16x8*)&WTb[(size_t)(od0 + od) * KD + k0 + kq] = o;
  }
}

// ---------------------------------------------------------------------------
// gemm_fused: Wh = x @ W (bf16 MFMA); epilogue emits fragment-ordered WhF
// plus exp tables esrcp (f32 pair) / edstp (packed bf16 pair).
// ---------------------------------------------------------------------------
__global__ __launch_bounds__(256) void gemm_fused(
    const float* __restrict__ X, const __hip_bfloat16* __restrict__ WTb,
    const float* __restrict__ a, short* __restrict__ WhF,
    float2* __restrict__ esrcp, u32* __restrict__ edstp) {
  __shared__ short As[64][72];
  __shared__ short Bs[64][72];
  const int t = threadIdx.x;
  const int lane = t & 63, w = t >> 6;
  const int col = lane & 15, kgrp = lane >> 4;
  const int bm = blockIdx.x * 64;
  const int h = blockIdx.y;

  const int am = t >> 2, ak = (t & 3) * 16;
  const int bn = t >> 2, bk = (t & 3) * 16;

  float4 xa[4];
  bf16x8 wb[2];
#pragma unroll
  for (int q = 0; q < 4; ++q)
    xa[q] = *(const float4*)&X[(size_t)(bm + am) * KD + ak + q * 4];
#pragma unroll
  for (int q = 0; q < 2; ++q)
    wb[q] = *(const bf16x8*)&WTb[(size_t)(h * 64 + bn) * KD + bk + q * 8];

  f32x4 acc[4] = {};

  for (int k0 = 0; k0 < KD; k0 += 64) {
#pragma unroll
    for (int q = 0; q < 2; ++q) {
      bf16x8 o;
#pragma unroll
      for (int u = 0; u < 4; ++u) {
        o[u] = tob(((const float*)&xa[q * 2])[u]);
        o[u + 4] = tob(((const float*)&xa[q * 2 + 1])[u]);
      }
      *(bf16x8*)&As[am][ak + q * 8] = o;
      *(bf16x8*)&Bs[bn][bk + q * 8] = wb[q];
    }
    __syncthreads();
    if (k0 + 64 < KD) {
      const int k1 = k0 + 64;
#pragma unroll
      for (int q = 0; q < 4; ++q)
        xa[q] = *(const float4*)&X[(size_t)(bm + am) * KD + k1 + ak + q * 4];
#pragma unroll
      for (int q = 0; q < 2; ++q)
        wb[q] = *(const bf16x8*)&WTb[(size_t)(h * 64 + bn) * KD + k1 + bk + q * 8];
    }
#pragma unroll
    for (int ks = 0; ks < 2; ++ks) {
      const bf16x8 af = *(const bf16x8*)&As[w * 16 + col][ks * 32 + kgrp * 8];
#pragma unroll
      for (int nt = 0; nt < 4; ++nt) {
        const bf16x8 bf = *(const bf16x8*)&Bs[nt * 16 + col][ks * 32 + kgrp * 8];
        acc[nt] = __builtin_amdgcn_mfma_f32_16x16x32_bf16(af, bf, acc[nt], 0, 0, 0);
      }
    }
    __syncthreads();
  }

  float asv[4], adv[4];
#pragma unroll
  for (int nt = 0; nt < 4; ++nt) {
    asv[nt] = a[nt * 16 + col];
    adv[nt] = a[64 + nt * 16 + col];
  }
  float ps[4], pd[4];
#pragma unroll
  for (int r = 0; r < 4; ++r) {
    float s1 = 0.f, s2 = 0.f;
#pragma unroll
    for (int nt = 0; nt < 4; ++nt) {
      s1 += acc[nt][r] * asv[nt];
      s2 += acc[nt][r] * adv[nt];
    }
    ps[r] = s1;
    pd[r] = s2;
  }
#pragma unroll
  for (int off = 1; off <= 8; off <<= 1) {
#pragma unroll
    for (int r = 0; r < 4; ++r) {
      ps[r] += __shfl_xor(ps[r], off);
      pd[r] += __shfl_xor(pd[r], off);
    }
  }
  {
    const size_t tbase = ((size_t)h * 32 + blockIdx.x) * 4096;
    const int lp = ((w & 1) * 2 + (kgrp >> 1)) * 16 + col;
    const int u0 = (kgrp & 1) * 4;
    const int slot_ks = w >> 1;
#pragma unroll
    for (int nt = 0; nt < 4; ++nt) {
      bf16x4 o;
#pragma unroll
      for (int r = 0; r < 4; ++r) o[r] = tob(acc[nt][r]);
      *(bf16x4*)&WhF[tbase + (size_t)(nt * 2 + slot_ks) * 512 + lp * 8 + u0] = o;
    }
  }
  if (col == 0) {
    const int mbase = bm + w * 16 + kgrp * 4;
#pragma unroll
    for (int r = 0; r < 4; ++r) {
      const int n = mbase + r;
      esrcp[h * NN + n] = make_float2(__expf(ps[r]), __expf(NEG * ps[r]));
      const u32 lo = (u32)(unsigned short)tob(__expf(pd[r]));
      const u32 hi = (u32)(unsigned short)tob(__expf(NEG * pd[r]));
      edstp[h * NN + n] = (hi << 16) | lo;
    }
  }
}

// ---------------------------------------------------------------------------
// attn_mfma: grid (32, 8), 512 threads = 8 waves = 2 m-halves x 4 j-quarters.
// 64 i-rows/block. B-fragments staged via global_load_lds (double-buffered,
// zero VGPR cost); p-gen in registers; 1 barrier per tile. Epilogue reduce
// aliases the (dead) staging LDS.
// ---------------------------------------------------------------------------
__global__ __launch_bounds__(512) void attn_mfma(
    const short* __restrict__ WhF, const unsigned char* __restrict__ adjbits,
    const float2* __restrict__ esrcp, const u32* __restrict__ edstp,
    float* __restrict__ out) {
  extern __shared__ __align__(16) char smem[];
  short* stage = (short*)smem;  // [4 jq][2 buf][8 slot][512] shorts = 64 KB
  float* red = (float*)smem;    // [8 wavegrp][32 row][66] f32, den at [64]

  const int t = threadIdx.x;
  const int lane = t & 63;
  const int wid = t >> 6;
  const int jq = wid >> 1;
  const int mh = wid & 1;
  const int col = lane & 15, kgrp = lane >> 4;
  const int h = blockIdx.y;
  const int i0 = blockIdx.x * 64;
  const int ib = i0 + mh * 32;

  const float2 e0 = esrcp[h * NN + ib + col];
  const float2 e1 = esrcp[h * NN + ib + 16 + col];
  const float A0 = e0.x, C0 = e0.y, A1 = e1.x, C1 = e1.y;
  const unsigned char* ab0 = adjbits + (size_t)(ib + col) * (NN / 8);
  const unsigned char* ab1 = adjbits + (size_t)(ib + 16 + col) * (NN / 8);

  bf16x8 ones;
#pragma unroll
  for (int u = 0; u < 8; ++u) ones[u] = (short)0x3F80;

  f32x4 acc[2][4] = {};
  f32x4 accd[2] = {};

  const short* tb = WhF + ((size_t)h * 32 + jq * 8) * 4096;
  const int jb = jq * 512;
  short* st0 = stage + (size_t)jq * (2 * 8 * 512);

  // ---- prologue: stage tile 0, prefetch regs tile 0 ----
#pragma unroll
  for (int s = 0; s < 4; ++s) {
    const int slot = mh * 4 + s;
    gl_lds16(tb + slot * 512 + lane * 8, st0 + slot * 512);
  }
  uint4 bd0, bd1, bd2, bd3;
  u64 aw0, aw1;
  {
    const int jj0 = jb + kgrp * 8;
    bd0 = *(const uint4*)&edstp[h * NN + jj0];
    bd1 = *(const uint4*)&edstp[h * NN + jj0 + 4];
    bd2 = *(const uint4*)&edstp[h * NN + jj0 + 32];
    bd3 = *(const uint4*)&edstp[h * NN + jj0 + 36];
    aw0 = *(const u64*)(ab0 + (jb >> 3));
    aw1 = *(const u64*)(ab1 + (jb >> 3));
  }
  __syncthreads();

#pragma unroll
  for (int tt = 0; tt < 8; ++tt) {
    short* scur = st0 + (tt & 1) * (8 * 512);
    short* snxt = st0 + ((tt + 1) & 1) * (8 * 512);
    // stage tile tt+1 (async, no dest registers)
    if (tt < 7) {
      const short* g = tb + (size_t)(tt + 1) * 4096;
#pragma unroll
      for (int s = 0; s < 4; ++s) {
        const int slot = mh * 4 + s;
        gl_lds16(g + slot * 512 + lane * 8, snxt + slot * 512);
      }
    }
    // prefetch regs for tile tt+1
    uint4 bn0, bn1, bn2, bn3;
    u64 an0 = 0, an1 = 0;
    if (tt < 7) {
      const int j1 = jb + (tt + 1) * 64;
      const int jj1 = j1 + kgrp * 8;
      bn0 = *(const uint4*)&edstp[h * NN + jj1];
      bn1 = *(const uint4*)&edstp[h * NN + jj1 + 4];
      bn2 = *(const uint4*)&edstp[h * NN + jj1 + 32];
      bn3 = *(const uint4*)&edstp[h * NN + jj1 + 36];
      an0 = *(const u64*)(ab0 + (j1 >> 3));
      an1 = *(const u64*)(ab1 + (j1 >> 3));
    }
    // p-gen (no transcendentals)
    bf16x8 af0[2], af1[2];
#pragma unroll
    for (int ks = 0; ks < 2; ++ks) {
      const u32 mb0 = (u32)(aw0 >> ((ks * 4 + kgrp) * 8)) & 0xffu;
      const u32 mb1 = (u32)(aw1 >> ((ks * 4 + kgrp) * 8)) & 0xffu;
      const uint4 q0 = ks ? bd2 : bd0;
      const uint4 q1 = ks ? bd3 : bd1;
      const u32 uw[8] = {q0.x, q0.y, q0.z, q0.w, q1.x, q1.y, q1.z, q1.w};
#pragma unroll
      for (int u2 = 0; u2 < 8; ++u2) {
        const float B = __uint_as_float(uw[u2] << 16);
        const float D = __uint_as_float(uw[u2] & 0xffff0000u);
        float p0 = fmaxf(A0 * B, C0 * D);
        float p1 = fmaxf(A1 * B, C1 * D);
        p0 = ((mb0 >> u2) & 1u) ? p0 : 0.f;
        p1 = ((mb1 >> u2) & 1u) ? p1 : 0.f;
        af0[ks][u2] = tob(p0);
        af1[ks][u2] = tob(p1);
      }
    }
    // MFMAs: denominators + 4 od-tiles (B frags from LDS, lane*16 linear)
    accd[0] = __builtin_amdgcn_mfma_f32_16x16x32_bf16(af0[0], ones, accd[0], 0, 0, 0);
    accd[0] = __builtin_amdgcn_mfma_f32_16x16x32_bf16(af0[1], ones, accd[0], 0, 0, 0);
    accd[1] = __builtin_amdgcn_mfma_f32_16x16x32_bf16(af1[0], ones, accd[1], 0, 0, 0);
    accd[1] = __builtin_amdgcn_mfma_f32_16x16x32_bf16(af1[1], ones, accd[1], 0, 0, 0);
#pragma unroll
    for (int nt = 0; nt < 4; ++nt) {
      const bf16x8 b0 = *(const bf16x8*)&scur[(nt * 2 + 0) * 512 + lane * 8];
      const bf16x8 b1 = *(const bf16x8*)&scur[(nt * 2 + 1) * 512 + lane * 8];
      acc[0][nt] = __builtin_amdgcn_mfma_f32_16x16x32_bf16(af0[0], b0, acc[0][nt], 0, 0, 0);
      acc[1][nt] = __builtin_amdgcn_mfma_f32_16x16x32_bf16(af1[0], b0, acc[1][nt], 0, 0, 0);
      acc[0][nt] = __builtin_amdgcn_mfma_f32_16x16x32_bf16(af0[1], b1, acc[0][nt], 0, 0, 0);
      acc[1][nt] = __builtin_amdgcn_mfma_f32_16x16x32_bf16(af1[1], b1, acc[1][nt], 0, 0, 0);
    }
    __syncthreads();  // drains staging loads; protects buffer swap
    if (tt < 7) {
      bd0 = bn0; bd1 = bn1; bd2 = bn2; bd3 = bn3;
      aw0 = an0; aw1 = an1;
    }
  }

  // ---- epilogue: per-wave partials into red (aliases dead staging) ----
  float* rw = red + (size_t)(mh * 4 + jq) * 32 * 66;
#pragma unroll
  for (int mt = 0; mt < 2; ++mt) {
#pragma unroll
    for (int nt = 0; nt < 4; ++nt)
#pragma unroll
      for (int r = 0; r < 4; ++r)
        rw[(mt * 16 + kgrp * 4 + r) * 66 + nt * 16 + col] = acc[mt][nt][r];
    if (col == 0) {
#pragma unroll
      for (int r = 0; r < 4; ++r)
        rw[(mt * 16 + kgrp * 4 + r) * 66 + 64] = accd[mt][r];
    }
  }
  __syncthreads();

  // ---- cross-jq reduce + normalize + store ----
  const int d = t & 63, rl = t >> 6;
#pragma unroll
  for (int rr = 0; rr < 8; ++rr) {
    const int row = rr * 8 + rl;
    const int m2 = row >> 5, r32 = row & 31;
    const float* rb = red + (size_t)(m2 * 4) * 32 * 66;
    float v = 0.f, dd = 0.f;
#pragma unroll
    for (int q = 0; q < 4; ++q) {
      v += rb[(q * 32 + r32) * 66 + d];
      dd += rb[(q * 32 + r32) * 66 + 64];
    }
    out[(size_t)(i0 + row) * ODIM + h * HD + d] = v / dd;
  }
}

// ---------------------------------------------------------------------------
extern "C" void kernel_launch(void* const* d_in, const int* in_sizes, int n_in,
                              void* d_out, int out_size, void* d_ws,
                              size_t ws_size, hipStream_t stream) {
  const float* x = (const float*)d_in[0];
  const int* adj = (const int*)d_in[1];
  const float* W = (const float*)d_in[2];
  const float* a = (const float*)d_in[3];
  float* out = (float*)d_out;

  char* ws = (char*)d_ws;
  short* WhF = (short*)ws;                                  // 2 MB
  __hip_bfloat16* WTb = (__hip_bfloat16*)(ws + (2 << 20));  // 512 KB
  unsigned short* bits =
      (unsigned short*)(ws + (2 << 20) + (512 << 10));      // 512 KB
  float2* esrcp = (float2*)(ws + (3 << 20));                // 128 KB
  u32* edstp = (u32*)(ws + (3 << 20) + (128 << 10));        // 64 KB

  prep<<<1088, 256, 0, stream>>>(W, adj, WTb, bits);
  gemm_fused<<<dim3(32, 8), 256, 0, stream>>>(x, WTb, a, WhF, esrcp, edstp);
  attn_mfma<<<dim3(32, 8), 512, 67584, stream>>>(
      WhF, (const unsigned char*)bits, esrcp, edstp, out);
}

// Round 7
// 36.184 us; speedup vs baseline: 6.1053x; 1.0148x over previous
//
#include <hip/hip_runtime.h>
#include <hip/hip_bf16.h>

#define NN 2048
#define KD 512
#define ODIM 512
#define NHEAD 8
#define HD 64
#define NEG 0.2f

typedef float f32x4 __attribute__((ext_vector_type(4)));
typedef short bf16x8 __attribute__((ext_vector_type(8)));
typedef short bf16x4 __attribute__((ext_vector_type(4)));
typedef unsigned long long u64;
typedef unsigned int u32;

__device__ __forceinline__ short tob(float f) {
  __hip_bfloat16 h = __float2bfloat16(f);
  return *reinterpret_cast<short*>(&h);
}

// async global -> LDS, 16 B per lane; LDS dest = uniform base + lane*16
__device__ __forceinline__ void gl_lds16(const void* g, void* l) {
  __builtin_amdgcn_global_load_lds(
      (const __attribute__((address_space(1))) u32*)g,
      (__attribute__((address_space(3))) u32*)l, 16, 0, 0);
}

// ---------------------------------------------------------------------------
// prep: blocks 0..63  -> WTb[od][k] = bf16(W[k][od])
//       blocks 64..   -> pack adj into 16-bit masks
// ---------------------------------------------------------------------------
__global__ __launch_bounds__(256) void prep(const float* __restrict__ W,
                                            const int* __restrict__ adj,
                                            __hip_bfloat16* __restrict__ WTb,
                                            unsigned short* __restrict__ bits) {
  const int b = blockIdx.x;
  const int t = threadIdx.x;
  if (b >= 64) {
    const int T = (b - 64) * 256 + t;
    const int row = T >> 7, g = T & 127;
    const int* p = adj + (size_t)row * NN + g * 16;
    u32 m = 0;
#pragma unroll
    for (int q = 0; q < 4; ++q) {
      const int4 v = *(const int4*)&p[q * 4];
      m |= (v.x > 0 ? 1u : 0u) << (q * 4);
      m |= (v.y > 0 ? 2u : 0u) << (q * 4);
      m |= (v.z > 0 ? 4u : 0u) << (q * 4);
      m |= (v.w > 0 ? 8u : 0u) << (q * 4);
    }
    bits[T] = (unsigned short)m;
    return;
  }
  __shared__ float tile[64][68];
  const int k0 = (b & 7) * 64, od0 = (b >> 3) * 64;
#pragma unroll
  for (int r = 0; r < 4; ++r) {
    const int flat = r * 256 + t;
    const int kk = flat >> 4, oq = (flat & 15) * 4;
    const float4 v = *(const float4*)&W[(size_t)(k0 + kk) * ODIM + od0 + oq];
    tile[kk][oq] = v.x;
    tile[kk][oq + 1] = v.y;
    tile[kk][oq + 2] = v.z;
    tile[kk][oq + 3] = v.w;
  }
  __syncthreads();
#pragma unroll
  for (int r = 0; r < 2; ++r) {
    const int flat = r * 256 + t;
    const int od = flat >> 3, kq = (flat & 7) * 8;
    bf16x8 o;
#pragma unroll
    for (int u = 0; u < 8; ++u) o[u] = tob(tile[kq + u][od]);
    *(bf16x8*)&WTb[(size_t)(od0 + od) * KD + k0 + kq] = o;
  }
}

// ---------------------------------------------------------------------------
// gemm_fused: Wh = x @ W (bf16 MFMA); epilogue emits fragment-ordered WhF
// plus exp tables esrcp (f32 pair) / edstp (packed bf16 pair).
// ---------------------------------------------------------------------------
__global__ __launch_bounds__(256) void gemm_fused(
    const float* __restrict__ X, const __hip_bfloat16* __restrict__ WTb,
    const float* __restrict__ a, short* __restrict__ WhF,
    float2* __restrict__ esrcp, u32* __restrict__ edstp) {
  __shared__ short As[64][72];
  __shared__ short Bs[64][72];
  const int t = threadIdx.x;
  const int lane = t & 63, w = t >> 6;
  const int col = lane & 15, kgrp = lane >> 4;
  const int bm = blockIdx.x * 64;
  const int h = blockIdx.y;

  const int am = t >> 2, ak = (t & 3) * 16;
  const int bn = t >> 2, bk = (t & 3) * 16;

  float4 xa[4];
  bf16x8 wb[2];
#pragma unroll
  for (int q = 0; q < 4; ++q)
    xa[q] = *(const float4*)&X[(size_t)(bm + am) * KD + ak + q * 4];
#pragma unroll
  for (int q = 0; q < 2; ++q)
    wb[q] = *(const bf16x8*)&WTb[(size_t)(h * 64 + bn) * KD + bk + q * 8];

  f32x4 acc[4] = {};

  for (int k0 = 0; k0 < KD; k0 += 64) {
#pragma unroll
    for (int q = 0; q < 2; ++q) {
      bf16x8 o;
#pragma unroll
      for (int u = 0; u < 4; ++u) {
        o[u] = tob(((const float*)&xa[q * 2])[u]);
        o[u + 4] = tob(((const float*)&xa[q * 2 + 1])[u]);
      }
      *(bf16x8*)&As[am][ak + q * 8] = o;
      *(bf16x8*)&Bs[bn][bk + q * 8] = wb[q];
    }
    __syncthreads();
    if (k0 + 64 < KD) {
      const int k1 = k0 + 64;
#pragma unroll
      for (int q = 0; q < 4; ++q)
        xa[q] = *(const float4*)&X[(size_t)(bm + am) * KD + k1 + ak + q * 4];
#pragma unroll
      for (int q = 0; q < 2; ++q)
        wb[q] = *(const bf16x8*)&WTb[(size_t)(h * 64 + bn) * KD + k1 + bk + q * 8];
    }
#pragma unroll
    for (int ks = 0; ks < 2; ++ks) {
      const bf16x8 af = *(const bf16x8*)&As[w * 16 + col][ks * 32 + kgrp * 8];
#pragma unroll
      for (int nt = 0; nt < 4; ++nt) {
        const bf16x8 bf = *(const bf16x8*)&Bs[nt * 16 + col][ks * 32 + kgrp * 8];
        acc[nt] = __builtin_amdgcn_mfma_f32_16x16x32_bf16(af, bf, acc[nt], 0, 0, 0);
      }
    }
    __syncthreads();
  }

  float asv[4], adv[4];
#pragma unroll
  for (int nt = 0; nt < 4; ++nt) {
    asv[nt] = a[nt * 16 + col];
    adv[nt] = a[64 + nt * 16 + col];
  }
  float ps[4], pd[4];
#pragma unroll
  for (int r = 0; r < 4; ++r) {
    float s1 = 0.f, s2 = 0.f;
#pragma unroll
    for (int nt = 0; nt < 4; ++nt) {
      s1 += acc[nt][r] * asv[nt];
      s2 += acc[nt][r] * adv[nt];
    }
    ps[r] = s1;
    pd[r] = s2;
  }
#pragma unroll
  for (int off = 1; off <= 8; off <<= 1) {
#pragma unroll
    for (int r = 0; r < 4; ++r) {
      ps[r] += __shfl_xor(ps[r], off);
      pd[r] += __shfl_xor(pd[r], off);
    }
  }
  {
    const size_t tbase = ((size_t)h * 32 + blockIdx.x) * 4096;
    const int lp = ((w & 1) * 2 + (kgrp >> 1)) * 16 + col;
    const int u0 = (kgrp & 1) * 4;
    const int slot_ks = w >> 1;
#pragma unroll
    for (int nt = 0; nt < 4; ++nt) {
      bf16x4 o;
#pragma unroll
      for (int r = 0; r < 4; ++r) o[r] = tob(acc[nt][r]);
      *(bf16x4*)&WhF[tbase + (size_t)(nt * 2 + slot_ks) * 512 + lp * 8 + u0] = o;
    }
  }
  if (col == 0) {
    const int mbase = bm + w * 16 + kgrp * 4;
#pragma unroll
    for (int r = 0; r < 4; ++r) {
      const int n = mbase + r;
      esrcp[h * NN + n] = make_float2(__expf(ps[r]), __expf(NEG * ps[r]));
      const u32 lo = (u32)(unsigned short)tob(__expf(pd[r]));
      const u32 hi = (u32)(unsigned short)tob(__expf(NEG * pd[r]));
      edstp[h * NN + n] = (hi << 16) | lo;
    }
  }
}

// ---------------------------------------------------------------------------
// attn_mfma: grid (64, 8), 256 threads = 4 waves = 4 j-quarters over the same
// 32 i-rows. NO barriers in the main loop: each wave owns a private LDS
// double-buffer, stages via global_load_lds, and synchronizes with per-wave
// counted s_waitcnt vmcnt(14) (8 staging + 4 edstp + 2 adj ops per tile).
// Loads for tile t+1 stay in flight across tile t's compute. Cross-jq reduce
// at the end behind the kernel's only two barriers (aliases staging LDS).
// ---------------------------------------------------------------------------
__global__ __launch_bounds__(256) void attn_mfma(
    const short* __restrict__ WhF, const unsigned char* __restrict__ adjbits,
    const float2* __restrict__ esrcp, const u32* __restrict__ edstp,
    float* __restrict__ out) {
  extern __shared__ __align__(16) char smem[];  // 64 KB: [4 jq][2 buf][8 KB]
  const int t = threadIdx.x;
  const int lane = t & 63;
  const int jq = t >> 6;
  const int col = lane & 15, kgrp = lane >> 4;
  const int h = blockIdx.y;
  const int i0 = blockIdx.x * 32;

  const short* tb = WhF + ((size_t)h * 32 + jq * 8) * 4096;
  const int jb = jq * 512;

  const float2 e0 = esrcp[h * NN + i0 + col];
  const float2 e1 = esrcp[h * NN + i0 + 16 + col];
  const float A0 = e0.x, C0 = e0.y, A1 = e1.x, C1 = e1.y;
  const unsigned char* ab0 = adjbits + (size_t)(i0 + col) * (NN / 8);
  const unsigned char* ab1 = adjbits + (size_t)(i0 + 16 + col) * (NN / 8);

  bf16x8 ones;
#pragma unroll
  for (int u = 0; u < 8; ++u) ones[u] = (short)0x3F80;

  f32x4 acc[2][4] = {};
  f32x4 accd[2] = {};

  uint4 bd[2][4];
  u64 aw[2][2];

  // ---- prologue: issue tile 0 (staging + regs) ----
  {
    short* sb = (short*)(smem + jq * 16384);
#pragma unroll
    for (int s = 0; s < 8; ++s) gl_lds16(tb + s * 512 + lane * 8, sb + s * 512);
    const int jj0 = jb + kgrp * 8;
    bd[0][0] = *(const uint4*)&edstp[h * NN + jj0];
    bd[0][1] = *(const uint4*)&edstp[h * NN + jj0 + 4];
    bd[0][2] = *(const uint4*)&edstp[h * NN + jj0 + 32];
    bd[0][3] = *(const uint4*)&edstp[h * NN + jj0 + 36];
    aw[0][0] = *(const u64*)(ab0 + (jb >> 3));
    aw[0][1] = *(const u64*)(ab1 + (jb >> 3));
  }

#pragma unroll
  for (int tt = 0; tt < 8; ++tt) {
    const int cur = tt & 1, nxt = cur ^ 1;
    // ---- issue tile tt+1 (14 vm ops), then wait for tile tt (vmcnt(14)) ----
    if (tt < 7) {
      const short* g = tb + (size_t)(tt + 1) * 4096;
      short* sb = (short*)(smem + jq * 16384 + nxt * 8192);
#pragma unroll
      for (int s = 0; s < 8; ++s)
        gl_lds16(g + s * 512 + lane * 8, sb + s * 512);
      const int j1 = jb + (tt + 1) * 64;
      const int jj1 = j1 + kgrp * 8;
      bd[nxt][0] = *(const uint4*)&edstp[h * NN + jj1];
      bd[nxt][1] = *(const uint4*)&edstp[h * NN + jj1 + 4];
      bd[nxt][2] = *(const uint4*)&edstp[h * NN + jj1 + 32];
      bd[nxt][3] = *(const uint4*)&edstp[h * NN + jj1 + 36];
      aw[nxt][0] = *(const u64*)(ab0 + (j1 >> 3));
      aw[nxt][1] = *(const u64*)(ab1 + (j1 >> 3));
      asm volatile("s_waitcnt vmcnt(14)" ::: "memory");
    } else {
      asm volatile("s_waitcnt vmcnt(0)" ::: "memory");
    }
    __builtin_amdgcn_sched_barrier(0);

    // ---- p-gen (no transcendentals) ----
    bf16x8 af0[2], af1[2];
#pragma unroll
    for (int ks = 0; ks < 2; ++ks) {
      const u32 mb0 = (u32)(aw[cur][0] >> ((ks * 4 + kgrp) * 8)) & 0xffu;
      const u32 mb1 = (u32)(aw[cur][1] >> ((ks * 4 + kgrp) * 8)) & 0xffu;
      const uint4 q0 = bd[cur][ks * 2];
      const uint4 q1 = bd[cur][ks * 2 + 1];
      const u32 uw[8] = {q0.x, q0.y, q0.z, q0.w, q1.x, q1.y, q1.z, q1.w};
#pragma unroll
      for (int u2 = 0; u2 < 8; ++u2) {
        const float B = __uint_as_float(uw[u2] << 16);
        const float D = __uint_as_float(uw[u2] & 0xffff0000u);
        float p0 = fmaxf(A0 * B, C0 * D);
        float p1 = fmaxf(A1 * B, C1 * D);
        p0 = ((mb0 >> u2) & 1u) ? p0 : 0.f;
        p1 = ((mb1 >> u2) & 1u) ? p1 : 0.f;
        af0[ks][u2] = tob(p0);
        af1[ks][u2] = tob(p1);
      }
    }

    // ---- MFMAs: denominators + 4 od-tiles (B frags from own LDS buf) ----
    const short* scur = (const short*)(smem + jq * 16384 + cur * 8192);
    accd[0] = __builtin_amdgcn_mfma_f32_16x16x32_bf16(af0[0], ones, accd[0], 0, 0, 0);
    accd[0] = __builtin_amdgcn_mfma_f32_16x16x32_bf16(af0[1], ones, accd[0], 0, 0, 0);
    accd[1] = __builtin_amdgcn_mfma_f32_16x16x32_bf16(af1[0], ones, accd[1], 0, 0, 0);
    accd[1] = __builtin_amdgcn_mfma_f32_16x16x32_bf16(af1[1], ones, accd[1], 0, 0, 0);
#pragma unroll
    for (int nt = 0; nt < 4; ++nt) {
      const bf16x8 b0 = *(const bf16x8*)&scur[(nt * 2 + 0) * 512 + lane * 8];
      const bf16x8 b1 = *(const bf16x8*)&scur[(nt * 2 + 1) * 512 + lane * 8];
      acc[0][nt] = __builtin_amdgcn_mfma_f32_16x16x32_bf16(af0[0], b0, acc[0][nt], 0, 0, 0);
      acc[1][nt] = __builtin_amdgcn_mfma_f32_16x16x32_bf16(af1[0], b0, acc[1][nt], 0, 0, 0);
      acc[0][nt] = __builtin_amdgcn_mfma_f32_16x16x32_bf16(af0[1], b1, acc[0][nt], 0, 0, 0);
      acc[1][nt] = __builtin_amdgcn_mfma_f32_16x16x32_bf16(af1[1], b1, acc[1][nt], 0, 0, 0);
    }
  }

  // ---- all waves done with staging; alias reduce buffer over it ----
  __syncthreads();
  float* red = (float*)smem;  // [4 jq][32 row][66]; den at col 64
  float* rw = red + (size_t)jq * 32 * 66;
#pragma unroll
  for (int mt = 0; mt < 2; ++mt) {
#pragma unroll
    for (int nt = 0; nt < 4; ++nt)
#pragma unroll
      for (int r = 0; r < 4; ++r)
        rw[(mt * 16 + kgrp * 4 + r) * 66 + nt * 16 + col] = acc[mt][nt][r];
    if (col == 0) {
#pragma unroll
      for (int r = 0; r < 4; ++r)
        rw[(mt * 16 + kgrp * 4 + r) * 66 + 64] = accd[mt][r];
    }
  }
  __syncthreads();

  // ---- cross-jq reduce + normalize + store ----
  const int d = t & 63, rl = t >> 6;
#pragma unroll
  for (int rr = 0; rr < 8; ++rr) {
    const int row = rr * 4 + rl;
    float v = 0.f, dd = 0.f;
#pragma unroll
    for (int q = 0; q < 4; ++q) {
      v += red[((size_t)q * 32 + row) * 66 + d];
      dd += red[((size_t)q * 32 + row) * 66 + 64];
    }
    out[(size_t)(i0 + row) * ODIM + h * HD + d] = v / dd;
  }
}

// ---------------------------------------------------------------------------
extern "C" void kernel_launch(void* const* d_in, const int* in_sizes, int n_in,
                              void* d_out, int out_size, void* d_ws,
                              size_t ws_size, hipStream_t stream) {
  const float* x = (const float*)d_in[0];
  const int* adj = (const int*)d_in[1];
  const float* W = (const float*)d_in[2];
  const float* a = (const float*)d_in[3];
  float* out = (float*)d_out;

  char* ws = (char*)d_ws;
  short* WhF = (short*)ws;                                  // 2 MB
  __hip_bfloat16* WTb = (__hip_bfloat16*)(ws + (2 << 20));  // 512 KB
  unsigned short* bits =
      (unsigned short*)(ws + (2 << 20) + (512 << 10));      // 512 KB
  float2* esrcp = (float2*)(ws + (3 << 20));                // 128 KB
  u32* edstp = (u32*)(ws + (3 << 20) + (128 << 10));        // 64 KB

  prep<<<1088, 256, 0, stream>>>(W, adj, WTb, bits);
  gemm_fused<<<dim3(32, 8), 256, 0, stream>>>(x, WTb, a, WhF, esrcp, edstp);
  attn_mfma<<<dim3(64, 8), 256, 65536, stream>>>(
      WhF, (const unsigned char*)bits, esrcp, edstp, out);
}